// Round 9
// baseline (162.635 us; speedup 1.0000x reference)
//
#include <hip/hip_runtime.h>
#include <cmath>

#define B_    32
#define T_    96
#define N_    512
#define F_    8
#define TF_   768
#define HID_  512
#define M_    16384
#define KIN_  1024
#define KS_   8        // K-split for kan

typedef short short8 __attribute__((ext_vector_type(8)));
typedef _Float16 half8 __attribute__((ext_vector_type(8)));
typedef float f32x4  __attribute__((ext_vector_type(4)));
typedef unsigned int  uintx4 __attribute__((ext_vector_type(4)));
typedef unsigned long long ulongx2 __attribute__((ext_vector_type(2)));
typedef unsigned short      ushort_t;
typedef unsigned int        uint_t;
typedef unsigned long long  ulong_t;

// workspace byte offsets (total <= 63.7 MB, unchanged footprint)
#define HT_B     0ull                 // bf16 ht[1024][16384]           = 33,554,432
#define WQ_B     33554432ull          // bf16 wq[8][9][4][4][64][8]     =  1,179,648
#define WB_B     34734080ull          // bf16 wb[1024][768]             =  1,572,864
#define SH_B     36306944ull          // xbf[16384][768] bf16 (25.2MB) OVERLAPS kanp[8][16384][64] fp16 (16.8MB)
#define WFQ_B    63569920ull          // fp16 wfq[6][2][2][4][64][8]    =     98,304

static __device__ inline uint_t  fbits(float f){ return __builtin_bit_cast(uint_t, f); }
static __device__ inline ushort_t f2b(float f){
    uint_t u = fbits(f);
    return (ushort_t)((u + 0x7fffu + ((u >> 16) & 1u)) >> 16);
}
static __device__ inline float b2f(ushort_t h){ return __builtin_bit_cast(float, (uint_t)h << 16); }
static __device__ inline ulong_t pack4(float4 v){      // RNE
    return (ulong_t)f2b(v.x) | ((ulong_t)f2b(v.y) << 16) |
           ((ulong_t)f2b(v.z) << 32) | ((ulong_t)f2b(v.w) << 48);
}
static __device__ inline ulong_t pack4t(float4 v){     // truncation (cheap)
    uint_t d0 = (fbits(v.x) >> 16) | (fbits(v.y) & 0xffff0000u);
    uint_t d1 = (fbits(v.z) >> 16) | (fbits(v.w) & 0xffff0000u);
    return (ulong_t)d0 | ((ulong_t)d1 << 32);
}
static __device__ inline float fast_tanh(float x){
    const float e = __expf(2.0f * x);
    return 1.0f - 2.0f / (e + 1.0f);
}
static __device__ inline void gload_lds16(const void* g, void* l){
    __builtin_amdgcn_global_load_lds(
        (const __attribute__((address_space(1))) unsigned int*)g,
        (__attribute__((address_space(3))) unsigned int*)l, 16, 0, 0);
}

// ---------------------------------------------------------------------------
// pack_wq: KAN weights, frag order, KS=8 (unchanged layout).
// linear frag index it = ss*4+t (0..31 bases, 32..35 silu) -> contiguous.
// ---------------------------------------------------------------------------
__global__ __launch_bounds__(256) void pack_wq(
    const float* __restrict__ base_w,
    const float* __restrict__ spline_w,
    const float* __restrict__ scaler,
    ushort_t* __restrict__ wq)
{
    const int e = blockIdx.x * 256 + threadIdx.x;   // 589824
    const int j    = e & 7;
    const int ln   = (e >> 3) & 63;
    const int ct   = (e >> 9) & 3;
    const int t    = (e >> 11) & 3;
    const int rest = e >> 13;        // 0..71
    const int ss   = rest % 9;
    const int ks   = rest / 9;
    const int o = ct * 16 + (ln & 15);
    const int g = ln >> 4;
    float v;
    if (ss < 8) {
        const int i = ks * 128 + ss * 16 + t * 4 + g;
        v = spline_w[(o * KIN_ + i) * 8 + j] * scaler[o * KIN_ + i];
    } else {
        const int i = ks * 128 + t * 32 + g * 8 + j;
        v = base_w[o * KIN_ + i];
    }
    wq[e] = f2b(v);
}

// ---------------------------------------------------------------------------
// pack_wb2: wb[1024][768] bf16 (rows 0..511 Wx, 512..1023 Wy)
// ---------------------------------------------------------------------------
__global__ __launch_bounds__(256) void pack_wb2(
    const float* __restrict__ Wx,
    const float* __restrict__ Wy,
    ushort_t* __restrict__ wb)
{
    const int e = blockIdx.x * 256 + threadIdx.x;   // 786432
    const float v = (e < 512 * TF_) ? Wx[e] : Wy[e - 512 * TF_];
    wb[e] = f2b(v);
}

// ---------------------------------------------------------------------------
// pack_wfq16: Wf frag order, fp16 (feeds f16 MFMA in final_v3).
// ---------------------------------------------------------------------------
__global__ __launch_bounds__(256) void pack_wfq16(
    const float* __restrict__ Wf, _Float16* __restrict__ wfq)
{
    const int e = blockIdx.x * 256 + threadIdx.x;   // 49152
    const int jj  = e & 7;
    const int ln  = (e >> 3) & 63;
    const int rt  = (e >> 9) & 3;
    const int s   = (e >> 11) & 1;
    const int wvt = (e >> 12) & 1;
    const int tb  = e >> 13;         // 0..5
    const int tf = tb * 128 + wvt * 64 + rt * 16 + (ln & 15);
    const int o  = s * 32 + (ln >> 4) * 8 + jj;
    wfq[e] = (_Float16)Wf[(size_t)tf * 64 + o];
}

// ---------------------------------------------------------------------------
// xcvt: xbf[m][k] bf16  <-  Xs[b][t][n][f] fp32  (unchanged)
// ---------------------------------------------------------------------------
__global__ __launch_bounds__(256) void xcvt_kernel(
    const float* __restrict__ Xs, ushort_t* __restrict__ xbf)
{
    __shared__ __align__(16) char lds[32 * 1552];
    const int tid = threadIdx.x;
    const int n0  = blockIdx.x * 32;
    const int bb  = blockIdx.y;
    const int nl  = (tid & 63) >> 1;
    const int f4  = (tid & 1) * 4;
    const int tq  = tid >> 6;
    #pragma unroll 4
    for (int u = 0; u < 24; u++) {
        const int t = u * 4 + tq;
        const float4 v = *(const float4*)(Xs + (size_t)bb * (T_ * N_ * F_)
                                             + (size_t)t * (N_ * F_)
                                             + (size_t)(n0 + nl) * F_ + f4);
        *(ulong_t*)(lds + nl * 1552 + t * 16 + f4 * 2) = pack4t(v);
    }
    __syncthreads();
    #pragma unroll 4
    for (int u = 0; u < 12; u++) {
        const int c   = u * 256 + tid;      // 0..3071
        const int row = c / 96;
        const int col = c - row * 96;
        const uintx4 val = *(const uintx4*)(lds + row * 1552 + col * 16);
        *(uintx4*)(xbf + (size_t)(bb * 512 + n0 + row) * TF_ + col * 8) = val;
    }
}

// ---------------------------------------------------------------------------
// gemm_tanh_v8 (m97 geometry): 128x128 tile, BK=64, 256 thr (4 waves),
// wave = 64m x 64j (acc 4x4) -> 16 ds_reads per 32 MFMA per wave-kt.
// Both operands via global_load_lds (linear dest, inverse-swizzled source).
// ---------------------------------------------------------------------------
__global__ __launch_bounds__(256) void gemm_tanh_v8(
    const ushort_t* __restrict__ xbf,
    const ushort_t* __restrict__ wb,
    const float* __restrict__ bias,
    ushort_t* __restrict__ ht, int z)
{
    __shared__ __align__(16) char smem[32768];   // A:[0,16K) B:[16K,32K)

    const int tid = threadIdx.x;
    const int wv  = tid >> 6;          // 0..3
    const int ln  = tid & 63;
    const int lr  = ln & 15;
    const int hi  = ln >> 4;
    const int wm  = wv >> 1;           // m-half (64 rows)
    const int wj  = wv & 1;            // j-half (64 cols)

    const int m0  = blockIdx.x * 128;
    const int jl0 = blockIdx.y * 128;
    const int j0  = z * 512 + jl0;

    const int srow8 = tid >> 3;        // 0..31
    const int sch   = tid & 7;

    f32x4 acc[4][4] = {};

    for (int kt = 0; kt < 12; kt++) {
        __syncthreads();
        #pragma unroll
        for (int s = 0; s < 4; s++) {
            const int row = s * 32 + srow8;
            const int ck = (sch ^ (row & 7)) * 8;
            gload_lds16(xbf + (size_t)(m0 + row) * TF_ + kt * 64 + ck,
                        smem + row * 128 + sch * 16);
            gload_lds16(wb + (size_t)(j0 + row) * TF_ + kt * 64 + ck,
                        smem + 16384 + row * 128 + sch * 16);
        }
        __syncthreads();

        #pragma unroll
        for (int h = 0; h < 2; h++) {
            const int g = h * 4 + hi;
            short8 a[4], b[4];
            #pragma unroll
            for (int rt = 0; rt < 4; rt++) {
                const int r = wm * 64 + rt * 16 + lr;
                a[rt] = *(short8*)(smem + r * 128 + ((g ^ (r & 7)) * 16));
            }
            #pragma unroll
            for (int ct = 0; ct < 4; ct++) {
                const int r = wj * 64 + ct * 16 + lr;
                b[ct] = *(short8*)(smem + 16384 + r * 128 + ((g ^ (r & 7)) * 16));
            }
            #pragma unroll
            for (int rt = 0; rt < 4; rt++)
                #pragma unroll
                for (int ct = 0; ct < 4; ct++)
                    acc[rt][ct] = __builtin_amdgcn_mfma_f32_16x16x32_bf16(
                        a[rt], b[ct], acc[rt][ct], 0, 0, 0);
        }
    }

    // epilogue: bias + tanh -> bf16 LDS [j 128][m 128] (16B-slot ^ (j&15)) -> ht
    __syncthreads();
    #pragma unroll
    for (int ct = 0; ct < 4; ct++) {
        const int j = wj * 64 + ct * 16 + lr;
        const float bvv = bias[jl0 + j];
        #pragma unroll
        for (int rt = 0; rt < 4; rt++) {
            const f32x4 v = acc[rt][ct];
            float4 tv;
            tv.x = fast_tanh(v[0] + bvv);
            tv.y = fast_tanh(v[1] + bvv);
            tv.z = fast_tanh(v[2] + bvv);
            tv.w = fast_tanh(v[3] + bvv);
            const int slot = wm * 8 + rt * 2 + (hi >> 1);   // 16B slot of m
            *(ulong_t*)(smem + j * 256 + ((slot ^ (j & 15)) * 16) + (hi & 1) * 8)
                = pack4(tv);
        }
    }
    __syncthreads();
    {
        const int j    = tid >> 1;           // 0..127
        const int half = tid & 1;
        ushort_t* dst = ht + (size_t)(j0 + j) * M_ + m0 + half * 64;
        #pragma unroll
        for (int w = 0; w < 8; w++) {
            const int slot = half * 8 + w;
            short8 val = *(short8*)(smem + j * 256 + ((slot ^ (j & 15)) * 16));
            *(short8*)(dst + w * 8) = val;
        }
    }
}

// ---------------------------------------------------------------------------
// kan_v6: zero-LDS, KS=8, grid (256,8); fully unrolled with depth-1
// register prefetch of B-frags + next ht scalar; setprio around MFMA quad.
// ---------------------------------------------------------------------------
static __device__ inline short8 eval_bases(float x)
{
    const float v = fmaf(x, 2.5f, 2.5f);
    float sf = floorf(v);
    sf = fminf(fmaxf(sf, 0.0f), 4.0f);
    const float u = v - sf;
    const int si = (int)sf;
    const float u2 = u * u, u3 = u2 * u;
    const float omu = 1.0f - u;
    const float omu3 = omu * omu * omu;
    const float Bb0 = omu3 * (1.0f / 6.0f);
    const float Bb3 = u3 * (1.0f / 6.0f);
    const float Bb1 = fmaf(0.5f, u3, 2.0f / 3.0f) - u2;
    const float Bb2 = 1.0f - Bb0 - Bb1 - Bb3;
    const uint_t d0 = (fbits(Bb0) >> 16) | (fbits(Bb1) & 0xffff0000u);
    const uint_t d1 = (fbits(Bb2) >> 16) | (fbits(Bb3) & 0xffff0000u);
    const ulong_t P = (ulong_t)d0 | ((ulong_t)d1 << 32);
    const int sh = si << 4;
    const ulong_t Plo = P << (sh & 63);
    const ulong_t Phi = P >> ((64 - sh) & 63);
    ulongx2 pr;
    pr.x = (si == 4) ? 0ull : Plo;
    pr.y = (si == 0) ? 0ull : ((si == 4) ? P : Phi);
    return __builtin_bit_cast(short8, pr);
}

__global__ __launch_bounds__(256) void kan_v6(
    const ushort_t* __restrict__ ht,
    const ushort_t* __restrict__ wq,
    _Float16* __restrict__ kanp)
{
    const int tid = threadIdx.x;
    const int wv  = tid >> 6;
    const int ln  = tid & 63;
    const int g   = ln >> 4;
    const int lr  = ln & 15;
    const int m0  = blockIdx.x * 64;
    const int ks  = blockIdx.y;
    const int iB  = ks * 128;
    const size_t r0 = (size_t)(m0 + wv * 16 + lr);

    const short8* wqf = (const short8*)wq + (size_t)ks * 9216 + ln;
    const ushort_t* htg  = ht + (size_t)(iB + g) * M_ + r0;       // bases
    const ushort_t* htg8 = ht + (size_t)(iB + g * 8) * M_ + r0;   // silu

    f32x4 acc[4] = {};

    // prologue prefetch: iter-0 frags + x
    short8 nb0 = wqf[0], nb1 = wqf[64], nb2 = wqf[128], nb3 = wqf[192];
    float  nx  = b2f(htg[0]);

    #pragma unroll
    for (int it = 0; it < 32; ++it) {
        const short8 b0 = nb0, b1 = nb1, b2 = nb2, b3 = nb3;
        const float  x  = nx;
        // prefetch next iteration (it==31 -> first silu frag set)
        const short8* bp = wqf + (size_t)(it + 1) * 256;
        nb0 = bp[0]; nb1 = bp[64]; nb2 = bp[128]; nb3 = bp[192];
        if (it < 31) {
            const int nit = it + 1;
            nx = b2f(htg[(size_t)((nit >> 2) * 16 + (nit & 3) * 4) * M_]);
        }
        const short8 a0 = eval_bases(x);
        __builtin_amdgcn_s_setprio(1);
        acc[0] = __builtin_amdgcn_mfma_f32_16x16x32_bf16(a0, b0, acc[0], 0, 0, 0);
        acc[1] = __builtin_amdgcn_mfma_f32_16x16x32_bf16(a0, b1, acc[1], 0, 0, 0);
        acc[2] = __builtin_amdgcn_mfma_f32_16x16x32_bf16(a0, b2, acc[2], 0, 0, 0);
        acc[3] = __builtin_amdgcn_mfma_f32_16x16x32_bf16(a0, b3, acc[3], 0, 0, 0);
        __builtin_amdgcn_s_setprio(0);
    }
    // silu supersteps (frag indices 32..35, already streaming through nb*)
    #pragma unroll
    for (int t = 0; t < 4; ++t) {
        const short8 b0 = nb0, b1 = nb1, b2 = nb2, b3 = nb3;
        if (t < 3) {
            const short8* bp = wqf + (size_t)(33 + t) * 256;
            nb0 = bp[0]; nb1 = bp[64]; nb2 = bp[128]; nb3 = bp[192];
        }
        uintx4 d;
        #pragma unroll
        for (int jj = 0; jj < 4; jj++) {
            const float x0 = b2f(htg8[(size_t)(t * 32 + 2 * jj)     * M_]);
            const float x1 = b2f(htg8[(size_t)(t * 32 + 2 * jj + 1) * M_]);
            const float s0 = x0 / (1.0f + __expf(-x0));
            const float s1 = x1 / (1.0f + __expf(-x1));
            d[jj] = (fbits(s0) >> 16) | (fbits(s1) & 0xffff0000u);
        }
        const short8 a0 = __builtin_bit_cast(short8, d);
        __builtin_amdgcn_s_setprio(1);
        acc[0] = __builtin_amdgcn_mfma_f32_16x16x32_bf16(a0, b0, acc[0], 0, 0, 0);
        acc[1] = __builtin_amdgcn_mfma_f32_16x16x32_bf16(a0, b1, acc[1], 0, 0, 0);
        acc[2] = __builtin_amdgcn_mfma_f32_16x16x32_bf16(a0, b2, acc[2], 0, 0, 0);
        acc[3] = __builtin_amdgcn_mfma_f32_16x16x32_bf16(a0, b3, acc[3], 0, 0, 0);
        __builtin_amdgcn_s_setprio(0);
    }

    // C layout: col (o) = ct*16+lr, row = g*4+q
    #pragma unroll
    for (int ct = 0; ct < 4; ct++) {
        const int o = ct * 16 + lr;
        #pragma unroll
        for (int q = 0; q < 4; q++) {
            const size_t row = (size_t)(m0 + wv * 16 + g * 4 + q);
            kanp[(size_t)ks * (M_ * 64) + row * 64 + o] = (_Float16)acc[ct][q];
        }
    }
}

// ---------------------------------------------------------------------------
// final_v3: fused reduce + GEMM.  B-frags = packed-f16 sum of the 8 kanp
// planes, fed directly to f16 MFMA (no conversions).
// out[b][t][n][f] = sum_o (sum_ks kanp[ks][m][o]) * Wf[tf][o] + bf[tf]
// ---------------------------------------------------------------------------
__global__ __launch_bounds__(256) void final_v3(
    const _Float16* __restrict__ kanp,
    const _Float16* __restrict__ wfq,
    const float* __restrict__ bf,
    float* __restrict__ out)
{
    const int tid = threadIdx.x;
    const int wv  = tid >> 6;
    const int ln  = tid & 63;
    const int lr  = ln & 15;
    const int hi  = ln >> 4;
    const int wvm = wv >> 1;
    const int wvt = wv & 1;
    const int mb  = blockIdx.x;
    const int tb  = blockIdx.y;

    f32x4 acc[4][4] = {};

    #pragma unroll
    for (int s = 0; s < 2; s++) {
        half8 afr[4], bfr[4];
        #pragma unroll
        for (int rt = 0; rt < 4; rt++) {
            const size_t idx = ((size_t)(((tb * 2 + wvt) * 2 + s) * 4 + rt)) * 64 + ln;
            afr[rt] = ((const half8*)wfq)[idx];
        }
        #pragma unroll
        for (int ct = 0; ct < 4; ct++) {
            const int m = mb * 128 + wvm * 64 + ct * 16 + lr;
            const _Float16* bp = kanp + (size_t)m * 64 + s * 32 + hi * 8;
            half8 sum = *(const half8*)bp;
            #pragma unroll
            for (int p = 1; p < KS_; p++)
                sum += *(const half8*)(bp + (size_t)p * (M_ * 64));
            bfr[ct] = sum;
        }
        #pragma unroll
        for (int rt = 0; rt < 4; rt++)
            #pragma unroll
            for (int ct = 0; ct < 4; ct++)
                acc[rt][ct] = __builtin_amdgcn_mfma_f32_16x16x32_f16(
                    afr[rt], bfr[ct], acc[rt][ct], 0, 0, 0);
    }

    #pragma unroll
    for (int rt = 0; rt < 4; rt++) {
        const int tf0 = tb * 128 + wvt * 64 + rt * 16 + hi * 4;
        const float4 b4 = *(const float4*)&bf[tf0];
        const int t  = tf0 >> 3;
        const int f0 = tf0 & 7;
        #pragma unroll
        for (int ct = 0; ct < 4; ct++) {
            const int m = mb * 128 + wvm * 64 + ct * 16 + lr;
            const int bb = m >> 9;
            const int n  = m & 511;
            const f32x4 v = acc[rt][ct];
            float4 o4 = make_float4(v[0] + b4.x, v[1] + b4.y, v[2] + b4.z, v[3] + b4.w);
            *(float4*)&out[(size_t)bb * (T_ * N_ * F_)
                           + (size_t)t * (N_ * F_)
                           + (size_t)n * F_ + f0] = o4;
        }
    }
}

// ---------------------------------------------------------------------------
extern "C" void kernel_launch(void* const* d_in, const int* in_sizes, int n_in,
                              void* d_out, int out_size, void* d_ws, size_t ws_size,
                              hipStream_t stream)
{
    const float* X      = (const float*)d_in[0];
    const float* Y      = (const float*)d_in[1];
    const float* Wx     = (const float*)d_in[2];
    const float* bx     = (const float*)d_in[3];
    const float* Wy     = (const float*)d_in[4];
    const float* by     = (const float*)d_in[5];
    const float* base_w = (const float*)d_in[6];
    const float* spline_w = (const float*)d_in[7];
    const float* spline_scaler = (const float*)d_in[8];
    const float* Wf     = (const float*)d_in[9];
    const float* bf     = (const float*)d_in[10];

    float* out = (float*)d_out;
    ushort_t* ht   = (ushort_t*)((char*)d_ws + HT_B);
    ushort_t* wq   = (ushort_t*)((char*)d_ws + WQ_B);
    ushort_t* wb   = (ushort_t*)((char*)d_ws + WB_B);
    ushort_t* xbf  = (ushort_t*)((char*)d_ws + SH_B);   // overlaps kanp
    _Float16* kanp = (_Float16*)((char*)d_ws + SH_B);
    _Float16* wfq  = (_Float16*)((char*)d_ws + WFQ_B);

    pack_wq<<<2304, 256, 0, stream>>>(base_w, spline_w, spline_scaler, wq);
    pack_wb2<<<3072, 256, 0, stream>>>(Wx, Wy, wb);
    pack_wfq16<<<192, 256, 0, stream>>>(Wf, wfq);

    // X half: convert then GEMM (xbf reused for Y afterwards)
    xcvt_kernel<<<dim3(16, 32), 256, 0, stream>>>(X, xbf);
    gemm_tanh_v8<<<dim3(128, 4), 256, 0, stream>>>(xbf, wb, bx, ht, 0);
    xcvt_kernel<<<dim3(16, 32), 256, 0, stream>>>(Y, xbf);
    gemm_tanh_v8<<<dim3(128, 4), 256, 0, stream>>>(xbf, wb, by, ht, 1);

    kan_v6<<<dim3(M_ / 64, KS_), 256, 0, stream>>>(ht, wq, kanp);
    final_v3<<<dim3(128, 6), 256, 0, stream>>>(kanp, wfq, bf, out);
}

// Round 10
// 151.884 us; speedup vs baseline: 1.0708x; 1.0708x over previous
//
#include <hip/hip_runtime.h>
#include <cmath>

#define B_    32
#define T_    96
#define N_    512
#define F_    8
#define TF_   768
#define HID_  512
#define M_    16384
#define KIN_  1024
#define KS_   8        // K-split for kan

typedef short short8 __attribute__((ext_vector_type(8)));
typedef _Float16 half8 __attribute__((ext_vector_type(8)));
typedef float f32x4  __attribute__((ext_vector_type(4)));
typedef unsigned int  uintx4 __attribute__((ext_vector_type(4)));
typedef unsigned long long ulongx2 __attribute__((ext_vector_type(2)));
typedef unsigned short      ushort_t;
typedef unsigned int        uint_t;
typedef unsigned long long  ulong_t;

// workspace byte offsets (total <= 63.7 MB, unchanged footprint)
#define HT_B     0ull                 // bf16 ht[1024][16384]           = 33,554,432
#define WQ_B     33554432ull          // bf16 wq[8][9][4][4][64][8]     =  1,179,648
#define WB_B     34734080ull          // bf16 wb[1024][768]             =  1,572,864
#define SH_B     36306944ull          // xbf[16384][768] bf16 (25.2MB) OVERLAPS kanp[8][16384][64] fp16 (16.8MB)
#define WFQ_B    63569920ull          // fp16 wfq[6][2][2][4][64][8]    =     98,304

static __device__ inline uint_t  fbits(float f){ return __builtin_bit_cast(uint_t, f); }
static __device__ inline ushort_t f2b(float f){
    uint_t u = fbits(f);
    return (ushort_t)((u + 0x7fffu + ((u >> 16) & 1u)) >> 16);
}
static __device__ inline float b2f(ushort_t h){ return __builtin_bit_cast(float, (uint_t)h << 16); }
static __device__ inline ulong_t pack4(float4 v){      // RNE
    return (ulong_t)f2b(v.x) | ((ulong_t)f2b(v.y) << 16) |
           ((ulong_t)f2b(v.z) << 32) | ((ulong_t)f2b(v.w) << 48);
}
static __device__ inline ulong_t pack4t(float4 v){     // truncation (cheap)
    uint_t d0 = (fbits(v.x) >> 16) | (fbits(v.y) & 0xffff0000u);
    uint_t d1 = (fbits(v.z) >> 16) | (fbits(v.w) & 0xffff0000u);
    return (ulong_t)d0 | ((ulong_t)d1 << 32);
}
static __device__ inline float fast_tanh(float x){
    const float e = __expf(2.0f * x);
    return 1.0f - 2.0f / (e + 1.0f);
}
static __device__ inline void gload_lds16(const void* g, void* l){
    __builtin_amdgcn_global_load_lds(
        (const __attribute__((address_space(1))) unsigned int*)g,
        (__attribute__((address_space(3))) unsigned int*)l, 16, 0, 0);
}

// ---------------------------------------------------------------------------
// pack_wq: KAN weights, frag order, KS=8 (unchanged layout).
// linear frag index it = ss*4+t (0..31 bases, 32..35 silu) -> contiguous 1KB.
// ---------------------------------------------------------------------------
__global__ __launch_bounds__(256) void pack_wq(
    const float* __restrict__ base_w,
    const float* __restrict__ spline_w,
    const float* __restrict__ scaler,
    ushort_t* __restrict__ wq)
{
    const int e = blockIdx.x * 256 + threadIdx.x;   // 589824
    const int j    = e & 7;
    const int ln   = (e >> 3) & 63;
    const int ct   = (e >> 9) & 3;
    const int t    = (e >> 11) & 3;
    const int rest = e >> 13;        // 0..71
    const int ss   = rest % 9;
    const int ks   = rest / 9;
    const int o = ct * 16 + (ln & 15);
    const int g = ln >> 4;
    float v;
    if (ss < 8) {
        const int i = ks * 128 + ss * 16 + t * 4 + g;
        v = spline_w[(o * KIN_ + i) * 8 + j] * scaler[o * KIN_ + i];
    } else {
        const int i = ks * 128 + t * 32 + g * 8 + j;
        v = base_w[o * KIN_ + i];
    }
    wq[e] = f2b(v);
}

// ---------------------------------------------------------------------------
// pack_wb2: wb[1024][768] bf16 (rows 0..511 Wx, 512..1023 Wy)
// ---------------------------------------------------------------------------
__global__ __launch_bounds__(256) void pack_wb2(
    const float* __restrict__ Wx,
    const float* __restrict__ Wy,
    ushort_t* __restrict__ wb)
{
    const int e = blockIdx.x * 256 + threadIdx.x;   // 786432
    const float v = (e < 512 * TF_) ? Wx[e] : Wy[e - 512 * TF_];
    wb[e] = f2b(v);
}

// ---------------------------------------------------------------------------
// pack_wfq16: Wf frag order, fp16 (feeds f16 MFMA in final_v3).
// ---------------------------------------------------------------------------
__global__ __launch_bounds__(256) void pack_wfq16(
    const float* __restrict__ Wf, _Float16* __restrict__ wfq)
{
    const int e = blockIdx.x * 256 + threadIdx.x;   // 49152
    const int jj  = e & 7;
    const int ln  = (e >> 3) & 63;
    const int rt  = (e >> 9) & 3;
    const int s   = (e >> 11) & 1;
    const int wvt = (e >> 12) & 1;
    const int tb  = e >> 13;         // 0..5
    const int tf = tb * 128 + wvt * 64 + rt * 16 + (ln & 15);
    const int o  = s * 32 + (ln >> 4) * 8 + jj;
    wfq[e] = (_Float16)Wf[(size_t)tf * 64 + o];
}

// ---------------------------------------------------------------------------
// xcvt: xbf[m][k] bf16  <-  Xs[b][t][n][f] fp32  (unchanged)
// ---------------------------------------------------------------------------
__global__ __launch_bounds__(256) void xcvt_kernel(
    const float* __restrict__ Xs, ushort_t* __restrict__ xbf)
{
    __shared__ __align__(16) char lds[32 * 1552];
    const int tid = threadIdx.x;
    const int n0  = blockIdx.x * 32;
    const int bb  = blockIdx.y;
    const int nl  = (tid & 63) >> 1;
    const int f4  = (tid & 1) * 4;
    const int tq  = tid >> 6;
    #pragma unroll 4
    for (int u = 0; u < 24; u++) {
        const int t = u * 4 + tq;
        const float4 v = *(const float4*)(Xs + (size_t)bb * (T_ * N_ * F_)
                                             + (size_t)t * (N_ * F_)
                                             + (size_t)(n0 + nl) * F_ + f4);
        *(ulong_t*)(lds + nl * 1552 + t * 16 + f4 * 2) = pack4t(v);
    }
    __syncthreads();
    #pragma unroll 4
    for (int u = 0; u < 12; u++) {
        const int c   = u * 256 + tid;      // 0..3071
        const int row = c / 96;
        const int col = c - row * 96;
        const uintx4 val = *(const uintx4*)(lds + row * 1552 + col * 16);
        *(uintx4*)(xbf + (size_t)(bb * 512 + n0 + row) * TF_ + col * 8) = val;
    }
}

// ---------------------------------------------------------------------------
// gemm_tanh_v7 (reverted: proven round-7/8 config).
// 128x128 tile, BK=64, 512 thr (8 waves, each 64m x 32j, acc 4x2).
// ---------------------------------------------------------------------------
__global__ __launch_bounds__(512, 2) void gemm_tanh_v7(
    const ushort_t* __restrict__ xbf,
    const ushort_t* __restrict__ wb,
    const float* __restrict__ bias,
    ushort_t* __restrict__ ht, int z)
{
    __shared__ __align__(16) char smem[32768];

    const int tid = threadIdx.x;
    const int wv  = tid >> 6;          // 0..7
    const int ln  = tid & 63;
    const int lr  = ln & 15;
    const int hi  = ln >> 4;
    const int wm  = wv >> 2;           // m-half
    const int wj  = wv & 3;            // j-quarter (32 cols)

    const int m0  = blockIdx.x * 128;
    const int jl0 = blockIdx.y * 128;
    const int j0  = z * 512 + jl0;

    const int r_l = ln >> 3;                    // row within 8-row region
    const int ck  = ((ln & 7) ^ r_l) * 8;       // inverse-swizzled src chunk

    f32x4 acc[4][2] = {};

    for (int kt = 0; kt < 12; kt++) {
        __syncthreads();
        #pragma unroll
        for (int s = 0; s < 2; s++) {
            const int reg = s * 8 + wv;          // 0..15
            const int row = reg * 8 + r_l;
            gload_lds16(xbf + (size_t)(m0 + row) * TF_ + kt * 64 + ck,
                        smem + reg * 1024 + ln * 16);
            gload_lds16(wb + (size_t)(j0 + row) * TF_ + kt * 64 + ck,
                        smem + 16384 + reg * 1024 + ln * 16);
        }
        __syncthreads();

        #pragma unroll
        for (int h = 0; h < 2; h++) {
            const int g = h * 4 + hi;
            short8 a[4], b[2];
            #pragma unroll
            for (int rt = 0; rt < 4; rt++) {
                const int r = wm * 64 + rt * 16 + lr;
                a[rt] = *(short8*)(smem + r * 128 + ((g ^ (r & 7)) * 16));
            }
            #pragma unroll
            for (int ct = 0; ct < 2; ct++) {
                const int r = wj * 32 + ct * 16 + lr;
                b[ct] = *(short8*)(smem + 16384 + r * 128 + ((g ^ (r & 7)) * 16));
            }
            #pragma unroll
            for (int rt = 0; rt < 4; rt++)
                #pragma unroll
                for (int ct = 0; ct < 2; ct++)
                    acc[rt][ct] = __builtin_amdgcn_mfma_f32_16x16x32_bf16(
                        a[rt], b[ct], acc[rt][ct], 0, 0, 0);
        }
    }

    // epilogue: tanh -> bf16 LDS [j 128][m 128] (16B-slot ^ (j&15)) -> ht
    __syncthreads();
    #pragma unroll
    for (int ct = 0; ct < 2; ct++) {
        const int j = wj * 32 + ct * 16 + lr;
        const float bvv = bias[jl0 + j];
        #pragma unroll
        for (int rt = 0; rt < 4; rt++) {
            const f32x4 v = acc[rt][ct];
            float4 tv;
            tv.x = fast_tanh(v[0] + bvv);
            tv.y = fast_tanh(v[1] + bvv);
            tv.z = fast_tanh(v[2] + bvv);
            tv.w = fast_tanh(v[3] + bvv);
            const int slot = wm * 8 + rt * 2 + (hi >> 1);
            *(ulong_t*)(smem + j * 256 + ((slot ^ (j & 15)) * 16) + (hi & 1) * 8)
                = pack4(tv);
        }
    }
    __syncthreads();
    {
        const int j  = tid >> 2;             // 0..127
        const int q4 = tid & 3;
        ushort_t* dst = ht + (size_t)(j0 + j) * M_ + m0 + q4 * 32;
        #pragma unroll
        for (int w = 0; w < 4; w++) {
            const int slot = q4 * 4 + w;
            short8 val = *(short8*)(smem + j * 256 + ((slot ^ (j & 15)) * 16));
            *(short8*)(dst + w * 8) = val;
        }
    }
}

// ---------------------------------------------------------------------------
// kan_v7: B-frags staged ONCE per block into LDS (4KB), shared by 4 waves;
// each wave covers 32 rows (acc[2][4]).  Grid (128, 8) = 1024 blocks.
// Cuts wq L2 traffic 8x vs v6 (1.2 GB -> 150 MB).
// ---------------------------------------------------------------------------
static __device__ inline short8 eval_bases(float x)
{
    const float v = fmaf(x, 2.5f, 2.5f);
    float sf = floorf(v);
    sf = fminf(sf, 4.0f);               // x > -1 always; only the +1.0 edge needs clamping
    const float u = v - sf;
    const int si = (int)sf;
    const float u2 = u * u, u3 = u2 * u;
    const float omu = 1.0f - u;
    const float omu3 = omu * omu * omu;
    const float Bb0 = omu3 * (1.0f / 6.0f);
    const float Bb3 = u3 * (1.0f / 6.0f);
    const float Bb1 = fmaf(0.5f, u3, 2.0f / 3.0f) - u2;
    const float Bb2 = 1.0f - Bb0 - Bb1 - Bb3;
    const uint_t d0 = (fbits(Bb0) >> 16) | (fbits(Bb1) & 0xffff0000u);
    const uint_t d1 = (fbits(Bb2) >> 16) | (fbits(Bb3) & 0xffff0000u);
    const ulong_t P = (ulong_t)d0 | ((ulong_t)d1 << 32);
    const int sh = si << 4;
    const ulong_t Plo = P << (sh & 63);
    const ulong_t Phi = P >> ((64 - sh) & 63);
    ulongx2 pr;
    pr.x = (si == 4) ? 0ull : Plo;
    pr.y = (si == 0) ? 0ull : ((si == 4) ? P : Phi);
    return __builtin_bit_cast(short8, pr);
}

__global__ __launch_bounds__(256) void kan_v7(
    const ushort_t* __restrict__ ht,
    const ushort_t* __restrict__ wq,
    _Float16* __restrict__ kanp)
{
    __shared__ __align__(16) char sb[4096];

    const int tid = threadIdx.x;
    const int wv  = tid >> 6;
    const int ln  = tid & 63;
    const int g   = ln >> 4;
    const int lr  = ln & 15;
    const int m0  = blockIdx.x * 128;
    const int ks  = blockIdx.y;
    const int iB  = ks * 128;
    const size_t r0 = (size_t)(m0 + wv * 32 + lr);

    const ushort_t* wqk = wq + (size_t)ks * 73728;     // this ks's 36x4 frags
    const ushort_t* hpA = ht + (size_t)(iB + g) * M_ + r0;       // bases
    const ushort_t* hpS = ht + (size_t)(iB + g * 8) * M_ + r0;   // silu

    f32x4 acc[2][4] = {};

    // prologue: stage frags of it=0 (wave wv stages ct=wv)
    gload_lds16(wqk + (size_t)wv * 512 + ln * 8, sb + wv * 1024 + ln * 16);
    __syncthreads();

    #pragma unroll
    for (int it = 0; it < 36; ++it) {
        // read this iteration's 4 B-frags from LDS
        const short8 b0 = *(short8*)(sb + 0 * 1024 + ln * 16);
        const short8 b1 = *(short8*)(sb + 1 * 1024 + ln * 16);
        const short8 b2 = *(short8*)(sb + 2 * 1024 + ln * 16);
        const short8 b3 = *(short8*)(sb + 3 * 1024 + ln * 16);
        __syncthreads();                       // all waves done reading sb
        if (it < 35)                           // stage next (overlaps eval)
            gload_lds16(wqk + (size_t)((it + 1) * 4 + wv) * 512 + ln * 8,
                        sb + wv * 1024 + ln * 16);

        short8 a0, a1;
        if (it < 32) {
            const size_t off = (size_t)(4 * it) * M_;
            a0 = eval_bases(b2f(hpA[off]));
            a1 = eval_bases(b2f(hpA[off + 16]));
        } else {
            const int t = it - 32;
            uintx4 d0v, d1v;
            #pragma unroll
            for (int jj = 0; jj < 4; jj++) {
                const size_t o0 = (size_t)(t * 32 + 2 * jj) * M_;
                const size_t o1 = (size_t)(t * 32 + 2 * jj + 1) * M_;
                const float x0 = b2f(hpS[o0]),      x1 = b2f(hpS[o1]);
                const float y0 = b2f(hpS[o0 + 16]), y1 = b2f(hpS[o1 + 16]);
                const float s0 = x0 / (1.0f + __expf(-x0));
                const float s1 = x1 / (1.0f + __expf(-x1));
                const float u0 = y0 / (1.0f + __expf(-y0));
                const float u1 = y1 / (1.0f + __expf(-y1));
                d0v[jj] = (fbits(s0) >> 16) | (fbits(s1) & 0xffff0000u);
                d1v[jj] = (fbits(u0) >> 16) | (fbits(u1) & 0xffff0000u);
            }
            a0 = __builtin_bit_cast(short8, d0v);
            a1 = __builtin_bit_cast(short8, d1v);
        }

        acc[0][0] = __builtin_amdgcn_mfma_f32_16x16x32_bf16(a0, b0, acc[0][0], 0, 0, 0);
        acc[0][1] = __builtin_amdgcn_mfma_f32_16x16x32_bf16(a0, b1, acc[0][1], 0, 0, 0);
        acc[0][2] = __builtin_amdgcn_mfma_f32_16x16x32_bf16(a0, b2, acc[0][2], 0, 0, 0);
        acc[0][3] = __builtin_amdgcn_mfma_f32_16x16x32_bf16(a0, b3, acc[0][3], 0, 0, 0);
        acc[1][0] = __builtin_amdgcn_mfma_f32_16x16x32_bf16(a1, b0, acc[1][0], 0, 0, 0);
        acc[1][1] = __builtin_amdgcn_mfma_f32_16x16x32_bf16(a1, b1, acc[1][1], 0, 0, 0);
        acc[1][2] = __builtin_amdgcn_mfma_f32_16x16x32_bf16(a1, b2, acc[1][2], 0, 0, 0);
        acc[1][3] = __builtin_amdgcn_mfma_f32_16x16x32_bf16(a1, b3, acc[1][3], 0, 0, 0);
        __syncthreads();                       // stage landed (vmcnt drained)
    }

    // C layout: col (o) = ct*16+lr, row = rt*16 + g*4 + q
    #pragma unroll
    for (int rt = 0; rt < 2; rt++) {
        #pragma unroll
        for (int ct = 0; ct < 4; ct++) {
            const int o = ct * 16 + lr;
            #pragma unroll
            for (int q = 0; q < 4; q++) {
                const size_t row = (size_t)(m0 + wv * 32 + rt * 16 + g * 4 + q);
                kanp[(size_t)ks * (M_ * 64) + row * 64 + o] = (_Float16)acc[rt][ct][q];
            }
        }
    }
}

// ---------------------------------------------------------------------------
// final_v3: fused reduce + GEMM (f16 MFMA), unchanged from round 9.
// ---------------------------------------------------------------------------
__global__ __launch_bounds__(256) void final_v3(
    const _Float16* __restrict__ kanp,
    const _Float16* __restrict__ wfq,
    const float* __restrict__ bf,
    float* __restrict__ out)
{
    const int tid = threadIdx.x;
    const int wv  = tid >> 6;
    const int ln  = tid & 63;
    const int lr  = ln & 15;
    const int hi  = ln >> 4;
    const int wvm = wv >> 1;
    const int wvt = wv & 1;
    const int mb  = blockIdx.x;
    const int tb  = blockIdx.y;

    f32x4 acc[4][4] = {};

    #pragma unroll
    for (int s = 0; s < 2; s++) {
        half8 afr[4], bfr[4];
        #pragma unroll
        for (int rt = 0; rt < 4; rt++) {
            const size_t idx = ((size_t)(((tb * 2 + wvt) * 2 + s) * 4 + rt)) * 64 + ln;
            afr[rt] = ((const half8*)wfq)[idx];
        }
        #pragma unroll
        for (int ct = 0; ct < 4; ct++) {
            const int m = mb * 128 + wvm * 64 + ct * 16 + lr;
            const _Float16* bp = kanp + (size_t)m * 64 + s * 32 + hi * 8;
            half8 sum = *(const half8*)bp;
            #pragma unroll
            for (int p = 1; p < KS_; p++)
                sum += *(const half8*)(bp + (size_t)p * (M_ * 64));
            bfr[ct] = sum;
        }
        #pragma unroll
        for (int rt = 0; rt < 4; rt++)
            #pragma unroll
            for (int ct = 0; ct < 4; ct++)
                acc[rt][ct] = __builtin_amdgcn_mfma_f32_16x16x32_f16(
                    afr[rt], bfr[ct], acc[rt][ct], 0, 0, 0);
    }

    #pragma unroll
    for (int rt = 0; rt < 4; rt++) {
        const int tf0 = tb * 128 + wvt * 64 + rt * 16 + hi * 4;
        const float4 b4 = *(const float4*)&bf[tf0];
        const int t  = tf0 >> 3;
        const int f0 = tf0 & 7;
        #pragma unroll
        for (int ct = 0; ct < 4; ct++) {
            const int m = mb * 128 + wvm * 64 + ct * 16 + lr;
            const int bb = m >> 9;
            const int n  = m & 511;
            const f32x4 v = acc[rt][ct];
            float4 o4 = make_float4(v[0] + b4.x, v[1] + b4.y, v[2] + b4.z, v[3] + b4.w);
            *(float4*)&out[(size_t)bb * (T_ * N_ * F_)
                           + (size_t)t * (N_ * F_)
                           + (size_t)n * F_ + f0] = o4;
        }
    }
}

// ---------------------------------------------------------------------------
extern "C" void kernel_launch(void* const* d_in, const int* in_sizes, int n_in,
                              void* d_out, int out_size, void* d_ws, size_t ws_size,
                              hipStream_t stream)
{
    const float* X      = (const float*)d_in[0];
    const float* Y      = (const float*)d_in[1];
    const float* Wx     = (const float*)d_in[2];
    const float* bx     = (const float*)d_in[3];
    const float* Wy     = (const float*)d_in[4];
    const float* by     = (const float*)d_in[5];
    const float* base_w = (const float*)d_in[6];
    const float* spline_w = (const float*)d_in[7];
    const float* spline_scaler = (const float*)d_in[8];
    const float* Wf     = (const float*)d_in[9];
    const float* bf     = (const float*)d_in[10];

    float* out = (float*)d_out;
    ushort_t* ht   = (ushort_t*)((char*)d_ws + HT_B);
    ushort_t* wq   = (ushort_t*)((char*)d_ws + WQ_B);
    ushort_t* wb   = (ushort_t*)((char*)d_ws + WB_B);
    ushort_t* xbf  = (ushort_t*)((char*)d_ws + SH_B);   // overlaps kanp
    _Float16* kanp = (_Float16*)((char*)d_ws + SH_B);
    _Float16* wfq  = (_Float16*)((char*)d_ws + WFQ_B);

    pack_wq<<<2304, 256, 0, stream>>>(base_w, spline_w, spline_scaler, wq);
    pack_wb2<<<3072, 256, 0, stream>>>(Wx, Wy, wb);
    pack_wfq16<<<192, 256, 0, stream>>>(Wf, wfq);

    // X half: convert then GEMM (xbf reused for Y afterwards)
    xcvt_kernel<<<dim3(16, 32), 256, 0, stream>>>(X, xbf);
    gemm_tanh_v7<<<dim3(128, 4), 512, 0, stream>>>(xbf, wb, bx, ht, 0);
    xcvt_kernel<<<dim3(16, 32), 256, 0, stream>>>(Y, xbf);
    gemm_tanh_v7<<<dim3(128, 4), 512, 0, stream>>>(xbf, wb, by, ht, 1);

    kan_v7<<<dim3(M_ / 128, KS_), 256, 0, stream>>>(ht, wq, kanp);
    final_v3<<<dim3(128, 6), 256, 0, stream>>>(kanp, wfq, bf, out);
}

// Round 11
// 138.718 us; speedup vs baseline: 1.1724x; 1.0949x over previous
//
#include <hip/hip_runtime.h>
#include <cmath>

#define B_    32
#define T_    96
#define N_    512
#define F_    8
#define TF_   768
#define HID_  512
#define M_    16384
#define KIN_  1024
#define KS_   8        // K-split for kan

typedef short short8 __attribute__((ext_vector_type(8)));
typedef _Float16 halfx8 __attribute__((ext_vector_type(8)));
typedef float f32x4  __attribute__((ext_vector_type(4)));
typedef unsigned int  uintx4 __attribute__((ext_vector_type(4)));
typedef unsigned long long ulongx2 __attribute__((ext_vector_type(2)));
typedef unsigned short      ushort_t;
typedef unsigned int        uint_t;
typedef unsigned long long  ulong_t;

// workspace byte offsets (total <= 63.7 MB)
#define HT_B     0ull                 // bf16 ht[1024][16384]           = 33,554,432
#define WQ_B     33554432ull          // bf16 wq[8][9][4][4][64][8]     =  1,179,648
#define WB_B     34734080ull          // bf16 wb[1024][768]             =  1,572,864
#define SH_B     36306944ull          // xbf bf16 (25.2MB) OVERLAPS kanp[8][16384][64] fp16 (16.8MB)
#define KANR_B   61472768ull          // bf16 kanr[16384][64]           =  2,097,152
#define WFQ_B    63569920ull          // bf16 wfq[6][2][2][4][64][8]    =     98,304

static __device__ inline uint_t  fbits(float f){ return __builtin_bit_cast(uint_t, f); }
static __device__ inline ushort_t f2b(float f){
    uint_t u = fbits(f);
    return (ushort_t)((u + 0x7fffu + ((u >> 16) & 1u)) >> 16);
}
static __device__ inline float b2f(ushort_t h){ return __builtin_bit_cast(float, (uint_t)h << 16); }
static __device__ inline ulong_t pack4(float4 v){      // RNE
    return (ulong_t)f2b(v.x) | ((ulong_t)f2b(v.y) << 16) |
           ((ulong_t)f2b(v.z) << 32) | ((ulong_t)f2b(v.w) << 48);
}
static __device__ inline ulong_t pack4t(float4 v){     // truncation (cheap)
    uint_t d0 = (fbits(v.x) >> 16) | (fbits(v.y) & 0xffff0000u);
    uint_t d1 = (fbits(v.z) >> 16) | (fbits(v.w) & 0xffff0000u);
    return (ulong_t)d0 | ((ulong_t)d1 << 32);
}
static __device__ inline float fast_tanh(float x){
    const float e = __expf(2.0f * x);
    return 1.0f - 2.0f / (e + 1.0f);
}
static __device__ inline void gload_lds16(const void* g, void* l){
    __builtin_amdgcn_global_load_lds(
        (const __attribute__((address_space(1))) unsigned int*)g,
        (__attribute__((address_space(3))) unsigned int*)l, 16, 0, 0);
}

// ---------------------------------------------------------------------------
// pack_wq: KAN weights, frag order, KS=8 (unchanged layout).
// ---------------------------------------------------------------------------
__global__ __launch_bounds__(256) void pack_wq(
    const float* __restrict__ base_w,
    const float* __restrict__ spline_w,
    const float* __restrict__ scaler,
    ushort_t* __restrict__ wq)
{
    const int e = blockIdx.x * 256 + threadIdx.x;   // 589824
    const int j    = e & 7;
    const int ln   = (e >> 3) & 63;
    const int ct   = (e >> 9) & 3;
    const int t    = (e >> 11) & 3;
    const int rest = e >> 13;        // 0..71
    const int ss   = rest % 9;
    const int ks   = rest / 9;
    const int o = ct * 16 + (ln & 15);
    const int g = ln >> 4;
    float v;
    if (ss < 8) {
        const int i = ks * 128 + ss * 16 + t * 4 + g;
        v = spline_w[(o * KIN_ + i) * 8 + j] * scaler[o * KIN_ + i];
    } else {
        const int i = ks * 128 + t * 32 + g * 8 + j;
        v = base_w[o * KIN_ + i];
    }
    wq[e] = f2b(v);
}

// ---------------------------------------------------------------------------
// pack_wb2: wb[1024][768] bf16 (rows 0..511 Wx, 512..1023 Wy)
// ---------------------------------------------------------------------------
__global__ __launch_bounds__(256) void pack_wb2(
    const float* __restrict__ Wx,
    const float* __restrict__ Wy,
    ushort_t* __restrict__ wb)
{
    const int e = blockIdx.x * 256 + threadIdx.x;   // 786432
    const float v = (e < 512 * TF_) ? Wx[e] : Wy[e - 512 * TF_];
    wb[e] = f2b(v);
}

// ---------------------------------------------------------------------------
// pack_wfq: Wf frag order, bf16 (r8-proven tail).
// ---------------------------------------------------------------------------
__global__ __launch_bounds__(256) void pack_wfq(
    const float* __restrict__ Wf, ushort_t* __restrict__ wfq)
{
    const int e = blockIdx.x * 256 + threadIdx.x;   // 49152
    const int jj  = e & 7;
    const int ln  = (e >> 3) & 63;
    const int rt  = (e >> 9) & 3;
    const int s   = (e >> 11) & 1;
    const int wvt = (e >> 12) & 1;
    const int tb  = e >> 13;         // 0..5
    const int tf = tb * 128 + wvt * 64 + rt * 16 + (ln & 15);
    const int o  = s * 32 + (ln >> 4) * 8 + jj;
    wfq[e] = f2b(Wf[(size_t)tf * 64 + o]);
}

// ---------------------------------------------------------------------------
// xcvt: xbf[m][k] bf16  <-  Xs[b][t][n][f] fp32  (unchanged)
// ---------------------------------------------------------------------------
__global__ __launch_bounds__(256) void xcvt_kernel(
    const float* __restrict__ Xs, ushort_t* __restrict__ xbf)
{
    __shared__ __align__(16) char lds[32 * 1552];
    const int tid = threadIdx.x;
    const int n0  = blockIdx.x * 32;
    const int bb  = blockIdx.y;
    const int nl  = (tid & 63) >> 1;
    const int f4  = (tid & 1) * 4;
    const int tq  = tid >> 6;
    #pragma unroll 4
    for (int u = 0; u < 24; u++) {
        const int t = u * 4 + tq;
        const float4 v = *(const float4*)(Xs + (size_t)bb * (T_ * N_ * F_)
                                             + (size_t)t * (N_ * F_)
                                             + (size_t)(n0 + nl) * F_ + f4);
        *(ulong_t*)(lds + nl * 1552 + t * 16 + f4 * 2) = pack4t(v);
    }
    __syncthreads();
    #pragma unroll 4
    for (int u = 0; u < 12; u++) {
        const int c   = u * 256 + tid;      // 0..3071
        const int row = c / 96;
        const int col = c - row * 96;
        const uintx4 val = *(const uintx4*)(lds + row * 1552 + col * 16);
        *(uintx4*)(xbf + (size_t)(bb * 512 + n0 + row) * TF_ + col * 8) = val;
    }
}

// ---------------------------------------------------------------------------
// gemm_tanh_v7 (unchanged, proven).
// ---------------------------------------------------------------------------
__global__ __launch_bounds__(512, 2) void gemm_tanh_v7(
    const ushort_t* __restrict__ xbf,
    const ushort_t* __restrict__ wb,
    const float* __restrict__ bias,
    ushort_t* __restrict__ ht, int z)
{
    __shared__ __align__(16) char smem[32768];

    const int tid = threadIdx.x;
    const int wv  = tid >> 6;          // 0..7
    const int ln  = tid & 63;
    const int lr  = ln & 15;
    const int hi  = ln >> 4;
    const int wm  = wv >> 2;           // m-half
    const int wj  = wv & 3;            // j-quarter (32 cols)

    const int m0  = blockIdx.x * 128;
    const int jl0 = blockIdx.y * 128;
    const int j0  = z * 512 + jl0;

    const int r_l = ln >> 3;                    // row within 8-row region
    const int ck  = ((ln & 7) ^ r_l) * 8;       // inverse-swizzled src chunk

    f32x4 acc[4][2] = {};

    for (int kt = 0; kt < 12; kt++) {
        __syncthreads();
        #pragma unroll
        for (int s = 0; s < 2; s++) {
            const int reg = s * 8 + wv;          // 0..15
            const int row = reg * 8 + r_l;
            gload_lds16(xbf + (size_t)(m0 + row) * TF_ + kt * 64 + ck,
                        smem + reg * 1024 + ln * 16);
            gload_lds16(wb + (size_t)(j0 + row) * TF_ + kt * 64 + ck,
                        smem + 16384 + reg * 1024 + ln * 16);
        }
        __syncthreads();

        #pragma unroll
        for (int h = 0; h < 2; h++) {
            const int g = h * 4 + hi;
            short8 a[4], b[2];
            #pragma unroll
            for (int rt = 0; rt < 4; rt++) {
                const int r = wm * 64 + rt * 16 + lr;
                a[rt] = *(short8*)(smem + r * 128 + ((g ^ (r & 7)) * 16));
            }
            #pragma unroll
            for (int ct = 0; ct < 2; ct++) {
                const int r = wj * 32 + ct * 16 + lr;
                b[ct] = *(short8*)(smem + 16384 + r * 128 + ((g ^ (r & 7)) * 16));
            }
            #pragma unroll
            for (int rt = 0; rt < 4; rt++)
                #pragma unroll
                for (int ct = 0; ct < 2; ct++)
                    acc[rt][ct] = __builtin_amdgcn_mfma_f32_16x16x32_bf16(
                        a[rt], b[ct], acc[rt][ct], 0, 0, 0);
        }
    }

    // epilogue: tanh -> bf16 LDS [j 128][m 128] (16B-slot ^ (j&15)) -> ht
    __syncthreads();
    #pragma unroll
    for (int ct = 0; ct < 2; ct++) {
        const int j = wj * 32 + ct * 16 + lr;
        const float bvv = bias[jl0 + j];
        #pragma unroll
        for (int rt = 0; rt < 4; rt++) {
            const f32x4 v = acc[rt][ct];
            float4 tv;
            tv.x = fast_tanh(v[0] + bvv);
            tv.y = fast_tanh(v[1] + bvv);
            tv.z = fast_tanh(v[2] + bvv);
            tv.w = fast_tanh(v[3] + bvv);
            const int slot = wm * 8 + rt * 2 + (hi >> 1);
            *(ulong_t*)(smem + j * 256 + ((slot ^ (j & 15)) * 16) + (hi & 1) * 8)
                = pack4(tv);
        }
    }
    __syncthreads();
    {
        const int j  = tid >> 2;             // 0..127
        const int q4 = tid & 3;
        ushort_t* dst = ht + (size_t)(j0 + j) * M_ + m0 + q4 * 32;
        #pragma unroll
        for (int w = 0; w < 4; w++) {
            const int slot = q4 * 4 + w;
            short8 val = *(short8*)(smem + j * 256 + ((slot ^ (j & 15)) * 16));
            *(short8*)(dst + w * 8) = val;
        }
    }
}

// ---------------------------------------------------------------------------
// kan_v8: ht tile staged in LDS (32KB, immediate-offset ds reads);
// weight frags double-buffered in LDS (2x4KB) -> 1 barrier/iter.
// 128 rows/block (4 waves x 32 rows, acc[2][4]); grid (128, 8); LDS 40KB.
// ---------------------------------------------------------------------------
static __device__ inline short8 eval_bases(float x)
{
    const float v = fmaf(x, 2.5f, 2.5f);
    float sf = floorf(v);
    sf = fminf(sf, 4.0f);               // x >= -1 always; only +1.0 edge clamps
    const float u = v - sf;
    const int si = (int)sf;
    const float u2 = u * u, u3 = u2 * u;
    const float omu = 1.0f - u;
    const float omu3 = omu * omu * omu;
    const float Bb0 = omu3 * (1.0f / 6.0f);
    const float Bb3 = u3 * (1.0f / 6.0f);
    const float Bb1 = fmaf(0.5f, u3, 2.0f / 3.0f) - u2;
    const float Bb2 = 1.0f - Bb0 - Bb1 - Bb3;
    const uint_t d0 = (fbits(Bb0) >> 16) | (fbits(Bb1) & 0xffff0000u);
    const uint_t d1 = (fbits(Bb2) >> 16) | (fbits(Bb3) & 0xffff0000u);
    const ulong_t P = (ulong_t)d0 | ((ulong_t)d1 << 32);
    const int sh = si << 4;
    const ulong_t Plo = P << (sh & 63);
    const ulong_t Phi = P >> ((64 - sh) & 63);
    ulongx2 pr;
    pr.x = (si == 4) ? 0ull : Plo;
    pr.y = (si == 0) ? 0ull : ((si == 4) ? P : Phi);
    return __builtin_bit_cast(short8, pr);
}

__global__ __launch_bounds__(256) void kan_v8(
    const ushort_t* __restrict__ ht,
    const ushort_t* __restrict__ wq,
    _Float16* __restrict__ kanp)
{
    __shared__ __align__(16) char lds[40960];   // hts[128][128]u16 (32K) + sb 2x4K

    const int tid = threadIdx.x;
    const int wv  = tid >> 6;
    const int ln  = tid & 63;
    const int g   = ln >> 4;
    const int lr  = ln & 15;
    const int m0  = blockIdx.x * 128;
    const int ks  = blockIdx.y;
    const int iB  = ks * 128;

    const ushort_t* wqk = wq + (size_t)ks * 73728;

    // prologue: stage ht tile (linear [il][row]) + sb buffer 0 (frag it=0)
    #pragma unroll
    for (int c = 0; c < 8; c++) {
        const int ll = wv * 8 + c;              // 0..31 (1KB calls)
        const int il = ll * 4 + (ln >> 4);
        const int r8 = (ln & 15) * 8;
        gload_lds16(ht + (size_t)(iB + il) * M_ + m0 + r8,
                    lds + ll * 1024 + ln * 16);
    }
    gload_lds16(wqk + (size_t)wv * 512 + ln * 8,
                lds + 32768 + wv * 1024 + ln * 16);
    __syncthreads();

    // per-lane LDS bases for x-reads (all per-iter offsets are immediates)
    const int hbA = g * 256  + wv * 64 + lr * 2;   // bases: + (ss*16+t*4)*256
    const int hbS = g * 2048 + wv * 64 + lr * 2;   // silu:  + (t*32+jj)*256

    f32x4 acc[2][4] = {};

    #pragma unroll
    for (int it = 0; it < 36; ++it) {
        const int p = it & 1;
        char* sb = lds + 32768 + p * 4096;
        const short8 b0 = *(short8*)(sb + 0 * 1024 + ln * 16);
        const short8 b1 = *(short8*)(sb + 1 * 1024 + ln * 16);
        const short8 b2 = *(short8*)(sb + 2 * 1024 + ln * 16);
        const short8 b3 = *(short8*)(sb + 3 * 1024 + ln * 16);

        // stage it+1's frags into the other buffer (drained at last barrier)
        if (it < 35)
            gload_lds16(wqk + (size_t)((it + 1) * 4 + wv) * 512 + ln * 8,
                        lds + 32768 + (p ^ 1) * 4096 + wv * 1024 + ln * 16);

        short8 a0, a1;
        if (it < 32) {
            const int off = hbA + ((it >> 2) * 16 + (it & 3) * 4) * 256;
            a0 = eval_bases(b2f(*(const ushort_t*)(lds + off)));
            a1 = eval_bases(b2f(*(const ushort_t*)(lds + off + 32)));
        } else {
            const int t = it - 32;
            uintx4 d0v, d1v;
            #pragma unroll
            for (int jj = 0; jj < 4; jj++) {
                const int o0 = hbS + (t * 32 + 2 * jj) * 256;
                const int o1 = o0 + 256;
                const float x0 = b2f(*(const ushort_t*)(lds + o0));
                const float x1 = b2f(*(const ushort_t*)(lds + o1));
                const float y0 = b2f(*(const ushort_t*)(lds + o0 + 32));
                const float y1 = b2f(*(const ushort_t*)(lds + o1 + 32));
                const float s0 = x0 / (1.0f + __expf(-x0));
                const float s1 = x1 / (1.0f + __expf(-x1));
                const float u0 = y0 / (1.0f + __expf(-y0));
                const float u1 = y1 / (1.0f + __expf(-y1));
                d0v[jj] = (fbits(s0) >> 16) | (fbits(s1) & 0xffff0000u);
                d1v[jj] = (fbits(u0) >> 16) | (fbits(u1) & 0xffff0000u);
            }
            a0 = __builtin_bit_cast(short8, d0v);
            a1 = __builtin_bit_cast(short8, d1v);
        }

        acc[0][0] = __builtin_amdgcn_mfma_f32_16x16x32_bf16(a0, b0, acc[0][0], 0, 0, 0);
        acc[0][1] = __builtin_amdgcn_mfma_f32_16x16x32_bf16(a0, b1, acc[0][1], 0, 0, 0);
        acc[0][2] = __builtin_amdgcn_mfma_f32_16x16x32_bf16(a0, b2, acc[0][2], 0, 0, 0);
        acc[0][3] = __builtin_amdgcn_mfma_f32_16x16x32_bf16(a0, b3, acc[0][3], 0, 0, 0);
        acc[1][0] = __builtin_amdgcn_mfma_f32_16x16x32_bf16(a1, b0, acc[1][0], 0, 0, 0);
        acc[1][1] = __builtin_amdgcn_mfma_f32_16x16x32_bf16(a1, b1, acc[1][1], 0, 0, 0);
        acc[1][2] = __builtin_amdgcn_mfma_f32_16x16x32_bf16(a1, b2, acc[1][2], 0, 0, 0);
        acc[1][3] = __builtin_amdgcn_mfma_f32_16x16x32_bf16(a1, b3, acc[1][3], 0, 0, 0);

        __syncthreads();   // sb[p] reads done everywhere + it+1 stage landed
    }

    // C layout: col (o) = ct*16+lr, row = rt*16 + g*4 + q
    #pragma unroll
    for (int rt = 0; rt < 2; rt++) {
        #pragma unroll
        for (int ct = 0; ct < 4; ct++) {
            const int o = ct * 16 + lr;
            #pragma unroll
            for (int q = 0; q < 4; q++) {
                const size_t row = (size_t)(m0 + wv * 32 + rt * 16 + g * 4 + q);
                kanp[(size_t)ks * (M_ * 64) + row * 64 + o] = (_Float16)acc[rt][ct][q];
            }
        }
    }
}

// ---------------------------------------------------------------------------
// reduce_kan: kanr[m][o] bf16 = sum_ks kanp_fp16[ks][m][o]  (r8-proven)
// ---------------------------------------------------------------------------
__global__ __launch_bounds__(256) void reduce_kan(
    const _Float16* __restrict__ kanp, ushort_t* __restrict__ kanr)
{
    const int e8 = blockIdx.x * 256 + threadIdx.x;   // 131072 threads
    const size_t base = (size_t)e8 * 8;
    float s[8] = {};
    #pragma unroll
    for (int p = 0; p < KS_; p++) {
        const halfx8 v = *(const halfx8*)(kanp + (size_t)p * (M_ * 64) + base);
        #pragma unroll
        for (int j = 0; j < 8; j++) s[j] += (float)v[j];
    }
    float4 s0 = make_float4(s[0], s[1], s[2], s[3]);
    float4 s1 = make_float4(s[4], s[5], s[6], s[7]);
    ulongx2 outv;
    outv.x = pack4(s0);
    outv.y = pack4(s1);
    *(ulongx2*)(kanr + base) = outv;
}

// ---------------------------------------------------------------------------
// final_v2 (r8-proven): out = kanr @ Wf^T + bf, MFMA, float4 stores.
// ---------------------------------------------------------------------------
__global__ __launch_bounds__(256) void final_v2(
    const ushort_t* __restrict__ kanr,
    const ushort_t* __restrict__ wfq,
    const float* __restrict__ bf,
    float* __restrict__ out)
{
    const int tid = threadIdx.x;
    const int wv  = tid >> 6;
    const int ln  = tid & 63;
    const int lr  = ln & 15;
    const int hi  = ln >> 4;
    const int wvm = wv >> 1;
    const int wvt = wv & 1;
    const int mb  = blockIdx.x;
    const int tb  = blockIdx.y;

    f32x4 acc[4][4] = {};

    #pragma unroll
    for (int s = 0; s < 2; s++) {
        short8 afr[4], bfr[4];
        #pragma unroll
        for (int rt = 0; rt < 4; rt++) {
            const size_t idx = ((size_t)(((tb * 2 + wvt) * 2 + s) * 4 + rt)) * 64 + ln;
            afr[rt] = ((const short8*)wfq)[idx];
        }
        #pragma unroll
        for (int ct = 0; ct < 4; ct++) {
            const int m = mb * 128 + wvm * 64 + ct * 16 + lr;
            bfr[ct] = *(const short8*)(kanr + (size_t)m * 64 + s * 32 + hi * 8);
        }
        #pragma unroll
        for (int rt = 0; rt < 4; rt++)
            #pragma unroll
            for (int ct = 0; ct < 4; ct++)
                acc[rt][ct] = __builtin_amdgcn_mfma_f32_16x16x32_bf16(
                    afr[rt], bfr[ct], acc[rt][ct], 0, 0, 0);
    }

    #pragma unroll
    for (int rt = 0; rt < 4; rt++) {
        const int tf0 = tb * 128 + wvt * 64 + rt * 16 + hi * 4;
        const float4 b4 = *(const float4*)&bf[tf0];
        const int t  = tf0 >> 3;
        const int f0 = tf0 & 7;
        #pragma unroll
        for (int ct = 0; ct < 4; ct++) {
            const int m = mb * 128 + wvm * 64 + ct * 16 + lr;
            const int bb = m >> 9;
            const int n  = m & 511;
            const f32x4 v = acc[rt][ct];
            float4 o4 = make_float4(v[0] + b4.x, v[1] + b4.y, v[2] + b4.z, v[3] + b4.w);
            *(float4*)&out[(size_t)bb * (T_ * N_ * F_)
                           + (size_t)t * (N_ * F_)
                           + (size_t)n * F_ + f0] = o4;
        }
    }
}

// ---------------------------------------------------------------------------
extern "C" void kernel_launch(void* const* d_in, const int* in_sizes, int n_in,
                              void* d_out, int out_size, void* d_ws, size_t ws_size,
                              hipStream_t stream)
{
    const float* X      = (const float*)d_in[0];
    const float* Y      = (const float*)d_in[1];
    const float* Wx     = (const float*)d_in[2];
    const float* bx     = (const float*)d_in[3];
    const float* Wy     = (const float*)d_in[4];
    const float* by     = (const float*)d_in[5];
    const float* base_w = (const float*)d_in[6];
    const float* spline_w = (const float*)d_in[7];
    const float* spline_scaler = (const float*)d_in[8];
    const float* Wf     = (const float*)d_in[9];
    const float* bf     = (const float*)d_in[10];

    float* out = (float*)d_out;
    ushort_t* ht   = (ushort_t*)((char*)d_ws + HT_B);
    ushort_t* wq   = (ushort_t*)((char*)d_ws + WQ_B);
    ushort_t* wb   = (ushort_t*)((char*)d_ws + WB_B);
    ushort_t* xbf  = (ushort_t*)((char*)d_ws + SH_B);   // overlaps kanp
    _Float16* kanp = (_Float16*)((char*)d_ws + SH_B);
    ushort_t* kanr = (ushort_t*)((char*)d_ws + KANR_B);
    ushort_t* wfq  = (ushort_t*)((char*)d_ws + WFQ_B);

    pack_wq<<<2304, 256, 0, stream>>>(base_w, spline_w, spline_scaler, wq);
    pack_wb2<<<3072, 256, 0, stream>>>(Wx, Wy, wb);
    pack_wfq<<<192, 256, 0, stream>>>(Wf, wfq);

    // X half: convert then GEMM (xbf reused for Y afterwards)
    xcvt_kernel<<<dim3(16, 32), 256, 0, stream>>>(X, xbf);
    gemm_tanh_v7<<<dim3(128, 4), 512, 0, stream>>>(xbf, wb, bx, ht, 0);
    xcvt_kernel<<<dim3(16, 32), 256, 0, stream>>>(Y, xbf);
    gemm_tanh_v7<<<dim3(128, 4), 512, 0, stream>>>(xbf, wb, by, ht, 1);

    kan_v8<<<dim3(M_ / 128, KS_), 256, 0, stream>>>(ht, wq, kanp);
    reduce_kan<<<512, 256, 0, stream>>>(kanp, kanr);
    final_v2<<<dim3(128, 6), 256, 0, stream>>>(kanr, wfq, bf, out);
}

// Round 12
// 137.149 us; speedup vs baseline: 1.1858x; 1.0114x over previous
//
#include <hip/hip_runtime.h>
#include <cmath>

#define B_    32
#define T_    96
#define N_    512
#define F_    8
#define TF_   768
#define HID_  512
#define M_    16384
#define KIN_  1024
#define KS_   8        // K-split for kan

typedef short short8 __attribute__((ext_vector_type(8)));
typedef _Float16 halfx8 __attribute__((ext_vector_type(8)));
typedef float f32x4  __attribute__((ext_vector_type(4)));
typedef float f32x2  __attribute__((ext_vector_type(2)));
typedef unsigned int  uintx4 __attribute__((ext_vector_type(4)));
typedef unsigned long long ulongx2 __attribute__((ext_vector_type(2)));
typedef unsigned short      ushort_t;
typedef unsigned int        uint_t;
typedef unsigned long long  ulong_t;

// workspace byte offsets (total <= 63.7 MB)
#define HT_B     0ull                 // bf16 ht[1024][16384]           = 33,554,432
#define WQ_B     33554432ull          // bf16 wq[8][9][4][4][64][8]     =  1,179,648
#define WB_B     34734080ull          // bf16 wb[1024][768]             =  1,572,864
#define SH_B     36306944ull          // xbf bf16 (25.2MB) OVERLAPS kanp[8][16384][64] fp16 (16.8MB)
#define KANR_B   61472768ull          // bf16 kanr[16384][64]           =  2,097,152
#define WFQ_B    63569920ull          // bf16 wfq[6][2][2][4][64][8]    =     98,304

static __device__ inline uint_t  fbits(float f){ return __builtin_bit_cast(uint_t, f); }
static __device__ inline ushort_t f2b(float f){
    uint_t u = fbits(f);
    return (ushort_t)((u + 0x7fffu + ((u >> 16) & 1u)) >> 16);
}
static __device__ inline float b2f(ushort_t h){ return __builtin_bit_cast(float, (uint_t)h << 16); }
static __device__ inline ulong_t pack4(float4 v){      // RNE
    return (ulong_t)f2b(v.x) | ((ulong_t)f2b(v.y) << 16) |
           ((ulong_t)f2b(v.z) << 32) | ((ulong_t)f2b(v.w) << 48);
}
static __device__ inline ulong_t pack4t(float4 v){     // truncation (cheap)
    uint_t d0 = (fbits(v.x) >> 16) | (fbits(v.y) & 0xffff0000u);
    uint_t d1 = (fbits(v.z) >> 16) | (fbits(v.w) & 0xffff0000u);
    return (ulong_t)d0 | ((ulong_t)d1 << 32);
}
static __device__ inline float fast_tanh(float x){
    const float e = __expf(2.0f * x);
    return 1.0f - 2.0f / (e + 1.0f);
}
static __device__ inline void gload_lds16(const void* g, void* l){
    __builtin_amdgcn_global_load_lds(
        (const __attribute__((address_space(1))) unsigned int*)g,
        (__attribute__((address_space(3))) unsigned int*)l, 16, 0, 0);
}

// ---------------------------------------------------------------------------
// pack_wq: KAN weights, frag order, KS=8.
// bases (ss<8): i = ks*128 + ss*16 + t*4 + g   (slot j = basis j)
// silu (ss==8): i = ks*128 + t*32 + j*4 + g    (REMAPPED so lane reads stride-4)
// ---------------------------------------------------------------------------
__global__ __launch_bounds__(256) void pack_wq(
    const float* __restrict__ base_w,
    const float* __restrict__ spline_w,
    const float* __restrict__ scaler,
    ushort_t* __restrict__ wq)
{
    const int e = blockIdx.x * 256 + threadIdx.x;   // 589824
    const int j    = e & 7;
    const int ln   = (e >> 3) & 63;
    const int ct   = (e >> 9) & 3;
    const int t    = (e >> 11) & 3;
    const int rest = e >> 13;        // 0..71
    const int ss   = rest % 9;
    const int ks   = rest / 9;
    const int o = ct * 16 + (ln & 15);
    const int g = ln >> 4;
    float v;
    if (ss < 8) {
        const int i = ks * 128 + ss * 16 + t * 4 + g;
        v = spline_w[(o * KIN_ + i) * 8 + j] * scaler[o * KIN_ + i];
    } else {
        const int i = ks * 128 + t * 32 + j * 4 + g;
        v = base_w[o * KIN_ + i];
    }
    wq[e] = f2b(v);
}

// ---------------------------------------------------------------------------
// pack_wb2: wb[1024][768] bf16 (rows 0..511 Wx, 512..1023 Wy)
// ---------------------------------------------------------------------------
__global__ __launch_bounds__(256) void pack_wb2(
    const float* __restrict__ Wx,
    const float* __restrict__ Wy,
    ushort_t* __restrict__ wb)
{
    const int e = blockIdx.x * 256 + threadIdx.x;   // 786432
    const float v = (e < 512 * TF_) ? Wx[e] : Wy[e - 512 * TF_];
    wb[e] = f2b(v);
}

// ---------------------------------------------------------------------------
// pack_wfq: Wf frag order, bf16 (r8-proven tail).
// ---------------------------------------------------------------------------
__global__ __launch_bounds__(256) void pack_wfq(
    const float* __restrict__ Wf, ushort_t* __restrict__ wfq)
{
    const int e = blockIdx.x * 256 + threadIdx.x;   // 49152
    const int jj  = e & 7;
    const int ln  = (e >> 3) & 63;
    const int rt  = (e >> 9) & 3;
    const int s   = (e >> 11) & 1;
    const int wvt = (e >> 12) & 1;
    const int tb  = e >> 13;         // 0..5
    const int tf = tb * 128 + wvt * 64 + rt * 16 + (ln & 15);
    const int o  = s * 32 + (ln >> 4) * 8 + jj;
    wfq[e] = f2b(Wf[(size_t)tf * 64 + o]);
}

// ---------------------------------------------------------------------------
// xcvt: xbf[m][k] bf16  <-  Xs[b][t][n][f] fp32  (unchanged)
// ---------------------------------------------------------------------------
__global__ __launch_bounds__(256) void xcvt_kernel(
    const float* __restrict__ Xs, ushort_t* __restrict__ xbf)
{
    __shared__ __align__(16) char lds[32 * 1552];
    const int tid = threadIdx.x;
    const int n0  = blockIdx.x * 32;
    const int bb  = blockIdx.y;
    const int nl  = (tid & 63) >> 1;
    const int f4  = (tid & 1) * 4;
    const int tq  = tid >> 6;
    #pragma unroll 4
    for (int u = 0; u < 24; u++) {
        const int t = u * 4 + tq;
        const float4 v = *(const float4*)(Xs + (size_t)bb * (T_ * N_ * F_)
                                             + (size_t)t * (N_ * F_)
                                             + (size_t)(n0 + nl) * F_ + f4);
        *(ulong_t*)(lds + nl * 1552 + t * 16 + f4 * 2) = pack4t(v);
    }
    __syncthreads();
    #pragma unroll 4
    for (int u = 0; u < 12; u++) {
        const int c   = u * 256 + tid;      // 0..3071
        const int row = c / 96;
        const int col = c - row * 96;
        const uintx4 val = *(const uintx4*)(lds + row * 1552 + col * 16);
        *(uintx4*)(xbf + (size_t)(bb * 512 + n0 + row) * TF_ + col * 8) = val;
    }
}

// ---------------------------------------------------------------------------
// gemm_tanh_v7 (unchanged, proven).
// ---------------------------------------------------------------------------
__global__ __launch_bounds__(512, 2) void gemm_tanh_v7(
    const ushort_t* __restrict__ xbf,
    const ushort_t* __restrict__ wb,
    const float* __restrict__ bias,
    ushort_t* __restrict__ ht, int z)
{
    __shared__ __align__(16) char smem[32768];

    const int tid = threadIdx.x;
    const int wv  = tid >> 6;          // 0..7
    const int ln  = tid & 63;
    const int lr  = ln & 15;
    const int hi  = ln >> 4;
    const int wm  = wv >> 2;           // m-half
    const int wj  = wv & 3;            // j-quarter (32 cols)

    const int m0  = blockIdx.x * 128;
    const int jl0 = blockIdx.y * 128;
    const int j0  = z * 512 + jl0;

    const int r_l = ln >> 3;                    // row within 8-row region
    const int ck  = ((ln & 7) ^ r_l) * 8;       // inverse-swizzled src chunk

    f32x4 acc[4][2] = {};

    for (int kt = 0; kt < 12; kt++) {
        __syncthreads();
        #pragma unroll
        for (int s = 0; s < 2; s++) {
            const int reg = s * 8 + wv;          // 0..15
            const int row = reg * 8 + r_l;
            gload_lds16(xbf + (size_t)(m0 + row) * TF_ + kt * 64 + ck,
                        smem + reg * 1024 + ln * 16);
            gload_lds16(wb + (size_t)(j0 + row) * TF_ + kt * 64 + ck,
                        smem + 16384 + reg * 1024 + ln * 16);
        }
        __syncthreads();

        #pragma unroll
        for (int h = 0; h < 2; h++) {
            const int g = h * 4 + hi;
            short8 a[4], b[2];
            #pragma unroll
            for (int rt = 0; rt < 4; rt++) {
                const int r = wm * 64 + rt * 16 + lr;
                a[rt] = *(short8*)(smem + r * 128 + ((g ^ (r & 7)) * 16));
            }
            #pragma unroll
            for (int ct = 0; ct < 2; ct++) {
                const int r = wj * 32 + ct * 16 + lr;
                b[ct] = *(short8*)(smem + 16384 + r * 128 + ((g ^ (r & 7)) * 16));
            }
            #pragma unroll
            for (int rt = 0; rt < 4; rt++)
                #pragma unroll
                for (int ct = 0; ct < 2; ct++)
                    acc[rt][ct] = __builtin_amdgcn_mfma_f32_16x16x32_bf16(
                        a[rt], b[ct], acc[rt][ct], 0, 0, 0);
        }
    }

    // epilogue: tanh -> bf16 LDS [j 128][m 128] (16B-slot ^ (j&15)) -> ht
    __syncthreads();
    #pragma unroll
    for (int ct = 0; ct < 2; ct++) {
        const int j = wj * 32 + ct * 16 + lr;
        const float bvv = bias[jl0 + j];
        #pragma unroll
        for (int rt = 0; rt < 4; rt++) {
            const f32x4 v = acc[rt][ct];
            float4 tv;
            tv.x = fast_tanh(v[0] + bvv);
            tv.y = fast_tanh(v[1] + bvv);
            tv.z = fast_tanh(v[2] + bvv);
            tv.w = fast_tanh(v[3] + bvv);
            const int slot = wm * 8 + rt * 2 + (hi >> 1);
            *(ulong_t*)(smem + j * 256 + ((slot ^ (j & 15)) * 16) + (hi & 1) * 8)
                = pack4(tv);
        }
    }
    __syncthreads();
    {
        const int j  = tid >> 2;             // 0..127
        const int q4 = tid & 3;
        ushort_t* dst = ht + (size_t)(j0 + j) * M_ + m0 + q4 * 32;
        #pragma unroll
        for (int w = 0; w < 4; w++) {
            const int slot = q4 * 4 + w;
            short8 val = *(short8*)(smem + j * 256 + ((slot ^ (j & 15)) * 16));
            *(short8*)(dst + w * 8) = val;
        }
    }
}

// ---------------------------------------------------------------------------
// kan_v9:
//  * hts tile in LDS with (il&3)<<5 XOR swizzle (conflict-free x-reads;
//    staged via inverse-swizzled gload source, linear LDS dest)
//  * weights register-staged 2 iters ahead -> ds_write (no vmcnt drain at
//    barriers from in-loop gload_lds)
//  * float2-vectorized closed-form eval; bases loop unroll 4 (code size)
// 128 rows/block (4 waves x 32 rows, acc[2][4]); grid (128, 8); LDS 40KB.
// ---------------------------------------------------------------------------
static __device__ inline short8 shift_pack(float b0, float b1, float b2, float b3, int si)
{
    const uint_t d0 = (fbits(b0) >> 16) | (fbits(b1) & 0xffff0000u);
    const uint_t d1 = (fbits(b2) >> 16) | (fbits(b3) & 0xffff0000u);
    const ulong_t P = (ulong_t)d0 | ((ulong_t)d1 << 32);
    const int sh = si << 4;
    const ulong_t Plo = P << (sh & 63);
    const ulong_t Phi = P >> ((64 - sh) & 63);
    ulongx2 pr;
    pr.x = (si == 4) ? 0ull : Plo;
    pr.y = (si == 0) ? 0ull : ((si == 4) ? P : Phi);
    return __builtin_bit_cast(short8, pr);
}

static __device__ inline void eval_bases2(float x0, float x1, short8& a0, short8& a1)
{
    f32x2 x = {x0, x1};
    f32x2 v = x * 2.5f + 2.5f;
    f32x2 sf = __builtin_elementwise_floor(v);
    sf = __builtin_elementwise_min(sf, (f32x2){4.0f, 4.0f});
    const f32x2 u  = v - sf;
    const f32x2 u2 = u * u;
    const f32x2 u3 = u2 * u;
    const f32x2 omu = 1.0f - u;
    const f32x2 omu3 = omu * omu * omu;
    const f32x2 B0 = omu3 * (1.0f / 6.0f);
    const f32x2 B3 = u3 * (1.0f / 6.0f);
    const f32x2 B1 = (u3 * 0.5f + (2.0f / 3.0f)) - u2;
    const f32x2 B2 = 1.0f - B0 - B1 - B3;
    a0 = shift_pack(B0[0], B1[0], B2[0], B3[0], (int)sf[0]);
    a1 = shift_pack(B0[1], B1[1], B2[1], B3[1], (int)sf[1]);
}

__global__ __launch_bounds__(256) void kan_v9(
    const ushort_t* __restrict__ ht,
    const ushort_t* __restrict__ wq,
    _Float16* __restrict__ kanp)
{
    __shared__ __align__(16) char lds[40960];   // hts 32K (swizzled) + 2x4K wbuf

    const int tid = threadIdx.x;
    const int wv  = tid >> 6;
    const int ln  = tid & 63;
    const int g   = ln >> 4;
    const int lr  = ln & 15;
    const int m0  = blockIdx.x * 128;
    const int ks  = blockIdx.y;
    const int iB  = ks * 128;

    const ushort_t* wqk = wq + (size_t)ks * 73728;

    // ---- prologue: stage hts (inverse-swizzled source), wbuf0, preload regs
    #pragma unroll
    for (int c = 0; c < 8; c++) {
        const int ll = wv * 8 + c;                   // 0..31
        const int il = ll * 4 + (ln >> 4);           // 0..127
        const int chunk = ln & 15;
        const int rowst = (chunk ^ ((il & 3) << 1)) * 8;   // inverse swizzle
        gload_lds16(ht + (size_t)(iB + il) * M_ + m0 + rowst,
                    lds + ll * 1024 + (ln & 15) * 16 + (ln >> 4) * 256);
    }
    gload_lds16(wqk + (size_t)wv * 512 + ln * 8,
                lds + 32768 + wv * 1024 + ln * 16);
    short8 wA = *(const short8*)(wqk + (size_t)(1 * 4 + wv) * 512 + ln * 8);
    short8 wB = *(const short8*)(wqk + (size_t)(2 * 4 + wv) * 512 + ln * 8);
    __syncthreads();

    // per-lane swizzled read bases (row0 = wv*32+lr, row1 = +16)
    const int hb0 = g * 256 + ((wv * 64 + lr * 2) ^ (g << 5));
    const int hb1 = g * 256 + ((wv * 64 + 32 + lr * 2) ^ (g << 5));

    f32x4 acc[2][4] = {};

    // ---- bases: 32 iterations (input = 4*it + g) ----
    #pragma unroll 4
    for (int it = 0; it < 32; ++it) {
        char* rb = lds + 32768 + (it & 1) * 4096;
        const short8 b0 = *(short8*)(rb + 0 * 1024 + ln * 16);
        const short8 b1 = *(short8*)(rb + 1 * 1024 + ln * 16);
        const short8 b2 = *(short8*)(rb + 2 * 1024 + ln * 16);
        const short8 b3 = *(short8*)(rb + 3 * 1024 + ln * 16);

        const float x0 = b2f(*(const ushort_t*)(lds + hb0 + it * 1024));
        const float x1 = b2f(*(const ushort_t*)(lds + hb1 + it * 1024));
        short8 a0, a1;
        eval_bases2(x0, x1, a0, a1);

        acc[0][0] = __builtin_amdgcn_mfma_f32_16x16x32_bf16(a0, b0, acc[0][0], 0, 0, 0);
        acc[0][1] = __builtin_amdgcn_mfma_f32_16x16x32_bf16(a0, b1, acc[0][1], 0, 0, 0);
        acc[0][2] = __builtin_amdgcn_mfma_f32_16x16x32_bf16(a0, b2, acc[0][2], 0, 0, 0);
        acc[0][3] = __builtin_amdgcn_mfma_f32_16x16x32_bf16(a0, b3, acc[0][3], 0, 0, 0);
        acc[1][0] = __builtin_amdgcn_mfma_f32_16x16x32_bf16(a1, b0, acc[1][0], 0, 0, 0);
        acc[1][1] = __builtin_amdgcn_mfma_f32_16x16x32_bf16(a1, b1, acc[1][1], 0, 0, 0);
        acc[1][2] = __builtin_amdgcn_mfma_f32_16x16x32_bf16(a1, b2, acc[1][2], 0, 0, 0);
        acc[1][3] = __builtin_amdgcn_mfma_f32_16x16x32_bf16(a1, b3, acc[1][3], 0, 0, 0);

        // write next iter's frags (data loaded 2 iters ago), reload pipeline
        *(short8*)(lds + 32768 + ((it + 1) & 1) * 4096 + wv * 1024 + ln * 16) = wA;
        wA = wB;
        wB = *(const short8*)(wqk + (size_t)((it + 3) * 4 + wv) * 512 + ln * 8);
        __syncthreads();
    }

    // ---- silu: 4 iterations (it = 32+t; input = t*32 + jj*4 + g) ----
    #pragma unroll
    for (int t = 0; t < 4; ++t) {
        const int it = 32 + t;
        char* rb = lds + 32768 + (it & 1) * 4096;
        const short8 b0 = *(short8*)(rb + 0 * 1024 + ln * 16);
        const short8 b1 = *(short8*)(rb + 1 * 1024 + ln * 16);
        const short8 b2 = *(short8*)(rb + 2 * 1024 + ln * 16);
        const short8 b3 = *(short8*)(rb + 3 * 1024 + ln * 16);

        uintx4 d0v, d1v;
        #pragma unroll
        for (int jw = 0; jw < 4; jw++) {
            const int o0 = hb0 + t * 8192 + (jw * 2) * 1024;
            const int o1 = hb0 + t * 8192 + (jw * 2 + 1) * 1024;
            const int p0 = hb1 + t * 8192 + (jw * 2) * 1024;
            const int p1 = hb1 + t * 8192 + (jw * 2 + 1) * 1024;
            const float x00 = b2f(*(const ushort_t*)(lds + o0));
            const float x01 = b2f(*(const ushort_t*)(lds + o1));
            const float x10 = b2f(*(const ushort_t*)(lds + p0));
            const float x11 = b2f(*(const ushort_t*)(lds + p1));
            const float s00 = x00 / (1.0f + __expf(-x00));
            const float s01 = x01 / (1.0f + __expf(-x01));
            const float s10 = x10 / (1.0f + __expf(-x10));
            const float s11 = x11 / (1.0f + __expf(-x11));
            d0v[jw] = (fbits(s00) >> 16) | (fbits(s01) & 0xffff0000u);
            d1v[jw] = (fbits(s10) >> 16) | (fbits(s11) & 0xffff0000u);
        }
        const short8 a0 = __builtin_bit_cast(short8, d0v);
        const short8 a1 = __builtin_bit_cast(short8, d1v);

        acc[0][0] = __builtin_amdgcn_mfma_f32_16x16x32_bf16(a0, b0, acc[0][0], 0, 0, 0);
        acc[0][1] = __builtin_amdgcn_mfma_f32_16x16x32_bf16(a0, b1, acc[0][1], 0, 0, 0);
        acc[0][2] = __builtin_amdgcn_mfma_f32_16x16x32_bf16(a0, b2, acc[0][2], 0, 0, 0);
        acc[0][3] = __builtin_amdgcn_mfma_f32_16x16x32_bf16(a0, b3, acc[0][3], 0, 0, 0);
        acc[1][0] = __builtin_amdgcn_mfma_f32_16x16x32_bf16(a1, b0, acc[1][0], 0, 0, 0);
        acc[1][1] = __builtin_amdgcn_mfma_f32_16x16x32_bf16(a1, b1, acc[1][1], 0, 0, 0);
        acc[1][2] = __builtin_amdgcn_mfma_f32_16x16x32_bf16(a1, b2, acc[1][2], 0, 0, 0);
        acc[1][3] = __builtin_amdgcn_mfma_f32_16x16x32_bf16(a1, b3, acc[1][3], 0, 0, 0);

        if (t < 3) {
            *(short8*)(lds + 32768 + ((it + 1) & 1) * 4096 + wv * 1024 + ln * 16) = wA;
            wA = wB;
            if (t == 0)
                wB = *(const short8*)(wqk + (size_t)(35 * 4 + wv) * 512 + ln * 8);
            __syncthreads();
        }
    }

    // C layout: col (o) = ct*16+lr, row = rt*16 + g*4 + q
    #pragma unroll
    for (int rt = 0; rt < 2; rt++) {
        #pragma unroll
        for (int ct = 0; ct < 4; ct++) {
            const int o = ct * 16 + lr;
            #pragma unroll
            for (int q = 0; q < 4; q++) {
                const size_t row = (size_t)(m0 + wv * 32 + rt * 16 + g * 4 + q);
                kanp[(size_t)ks * (M_ * 64) + row * 64 + o] = (_Float16)acc[rt][ct][q];
            }
        }
    }
}

// ---------------------------------------------------------------------------
// reduce_kan: kanr[m][o] bf16 = sum_ks kanp_fp16[ks][m][o]  (r8-proven)
// ---------------------------------------------------------------------------
__global__ __launch_bounds__(256) void reduce_kan(
    const _Float16* __restrict__ kanp, ushort_t* __restrict__ kanr)
{
    const int e8 = blockIdx.x * 256 + threadIdx.x;   // 131072 threads
    const size_t base = (size_t)e8 * 8;
    float s[8] = {};
    #pragma unroll
    for (int p = 0; p < KS_; p++) {
        const halfx8 v = *(const halfx8*)(kanp + (size_t)p * (M_ * 64) + base);
        #pragma unroll
        for (int j = 0; j < 8; j++) s[j] += (float)v[j];
    }
    float4 s0 = make_float4(s[0], s[1], s[2], s[3]);
    float4 s1 = make_float4(s[4], s[5], s[6], s[7]);
    ulongx2 outv;
    outv.x = pack4(s0);
    outv.y = pack4(s1);
    *(ulongx2*)(kanr + base) = outv;
}

// ---------------------------------------------------------------------------
// final_v2 (r8-proven): out = kanr @ Wf^T + bf, MFMA, float4 stores.
// ---------------------------------------------------------------------------
__global__ __launch_bounds__(256) void final_v2(
    const ushort_t* __restrict__ kanr,
    const ushort_t* __restrict__ wfq,
    const float* __restrict__ bf,
    float* __restrict__ out)
{
    const int tid = threadIdx.x;
    const int wv  = tid >> 6;
    const int ln  = tid & 63;
    const int lr  = ln & 15;
    const int hi  = ln >> 4;
    const int wvm = wv >> 1;
    const int wvt = wv & 1;
    const int mb  = blockIdx.x;
    const int tb  = blockIdx.y;

    f32x4 acc[4][4] = {};

    #pragma unroll
    for (int s = 0; s < 2; s++) {
        short8 afr[4], bfr[4];
        #pragma unroll
        for (int rt = 0; rt < 4; rt++) {
            const size_t idx = ((size_t)(((tb * 2 + wvt) * 2 + s) * 4 + rt)) * 64 + ln;
            afr[rt] = ((const short8*)wfq)[idx];
        }
        #pragma unroll
        for (int ct = 0; ct < 4; ct++) {
            const int m = mb * 128 + wvm * 64 + ct * 16 + lr;
            bfr[ct] = *(const short8*)(kanr + (size_t)m * 64 + s * 32 + hi * 8);
        }
        #pragma unroll
        for (int rt = 0; rt < 4; rt++)
            #pragma unroll
            for (int ct = 0; ct < 4; ct++)
                acc[rt][ct] = __builtin_amdgcn_mfma_f32_16x16x32_bf16(
                    afr[rt], bfr[ct], acc[rt][ct], 0, 0, 0);
    }

    #pragma unroll
    for (int rt = 0; rt < 4; rt++) {
        const int tf0 = tb * 128 + wvt * 64 + rt * 16 + hi * 4;
        const float4 b4 = *(const float4*)&bf[tf0];
        const int t  = tf0 >> 3;
        const int f0 = tf0 & 7;
        #pragma unroll
        for (int ct = 0; ct < 4; ct++) {
            const int m = mb * 128 + wvm * 64 + ct * 16 + lr;
            const int bb = m >> 9;
            const int n  = m & 511;
            const f32x4 v = acc[rt][ct];
            float4 o4 = make_float4(v[0] + b4.x, v[1] + b4.y, v[2] + b4.z, v[3] + b4.w);
            *(float4*)&out[(size_t)bb * (T_ * N_ * F_)
                           + (size_t)t * (N_ * F_)
                           + (size_t)n * F_ + f0] = o4;
        }
    }
}

// ---------------------------------------------------------------------------
extern "C" void kernel_launch(void* const* d_in, const int* in_sizes, int n_in,
                              void* d_out, int out_size, void* d_ws, size_t ws_size,
                              hipStream_t stream)
{
    const float* X      = (const float*)d_in[0];
    const float* Y      = (const float*)d_in[1];
    const float* Wx     = (const float*)d_in[2];
    const float* bx     = (const float*)d_in[3];
    const float* Wy     = (const float*)d_in[4];
    const float* by     = (const float*)d_in[5];
    const float* base_w = (const float*)d_in[6];
    const float* spline_w = (const float*)d_in[7];
    const float* spline_scaler = (const float*)d_in[8];
    const float* Wf     = (const float*)d_in[9];
    const float* bf     = (const float*)d_in[10];

    float* out = (float*)d_out;
    ushort_t* ht   = (ushort_t*)((char*)d_ws + HT_B);
    ushort_t* wq   = (ushort_t*)((char*)d_ws + WQ_B);
    ushort_t* wb   = (ushort_t*)((char*)d_ws + WB_B);
    ushort_t* xbf  = (ushort_t*)((char*)d_ws + SH_B);   // overlaps kanp
    _Float16* kanp = (_Float16*)((char*)d_ws + SH_B);
    ushort_t* kanr = (ushort_t*)((char*)d_ws + KANR_B);
    ushort_t* wfq  = (ushort_t*)((char*)d_ws + WFQ_B);

    pack_wq<<<2304, 256, 0, stream>>>(base_w, spline_w, spline_scaler, wq);
    pack_wb2<<<3072, 256, 0, stream>>>(Wx, Wy, wb);
    pack_wfq<<<192, 256, 0, stream>>>(Wf, wfq);

    // X half: convert then GEMM (xbf reused for Y afterwards)
    xcvt_kernel<<<dim3(16, 32), 256, 0, stream>>>(X, xbf);
    gemm_tanh_v7<<<dim3(128, 4), 512, 0, stream>>>(xbf, wb, bx, ht, 0);
    xcvt_kernel<<<dim3(16, 32), 256, 0, stream>>>(Y, xbf);
    gemm_tanh_v7<<<dim3(128, 4), 512, 0, stream>>>(xbf, wb, by, ht, 1);

    kan_v9<<<dim3(M_ / 128, KS_), 256, 0, stream>>>(ht, wq, kanp);
    reduce_kan<<<512, 256, 0, stream>>>(kanp, kanr);
    final_v2<<<dim3(128, 6), 256, 0, stream>>>(kanr, wfq, bf, out);
}

// Round 14
// 127.648 us; speedup vs baseline: 1.2741x; 1.0744x over previous
//
#include <hip/hip_runtime.h>
#include <cmath>

#define B_    32
#define T_    96
#define N_    512
#define F_    8
#define TF_   768
#define HID_  512
#define M_    16384
#define KIN_  1024
#define KS_   8        // K-split for kan

typedef short short8 __attribute__((ext_vector_type(8)));
typedef _Float16 halfx8 __attribute__((ext_vector_type(8)));
typedef float f32x4  __attribute__((ext_vector_type(4)));
typedef float f32x2  __attribute__((ext_vector_type(2)));
typedef unsigned int  uintx4 __attribute__((ext_vector_type(4)));
typedef unsigned long long ulongx2 __attribute__((ext_vector_type(2)));
typedef unsigned short      ushort_t;
typedef unsigned int        uint_t;
typedef unsigned long long  ulong_t;

// workspace byte offsets (total <= 63.7 MB)
#define HT_B     0ull                 // bf16 ht[1024][16384]           = 33,554,432
#define WQ_B     33554432ull          // bf16 wq[8][8][4][4][64][8]     =  1,048,576
#define WB_B     34734080ull          // bf16 wb[1024][768]             =  1,572,864
#define SH_B     36306944ull          // xbf bf16 (25.2MB) OVERLAPS kanp[8][16384][64] fp16 (16.8MB)
#define KANR_B   61472768ull          // bf16 kanr[16384][64]           =  2,097,152
#define WFQ_B    63569920ull          // bf16 wfq[6][2][2][4][64][8]    =     98,304

// silu(x) ~= sum_k KC[k]*B_k(x) on (-1,1): quasi-interpolant at basis centers
// z_k = -1.4 + 0.4k ; c_k = silu(z_k) - (0.4^2/6)*silu''(z_k).  max err ~2e-4.
__device__ __constant__ float KC[8] = {
    -0.2818252f, -0.2770046f, -0.2237417f, -0.1031025f,
     0.0968975f,  0.3762583f,  0.7229954f,  1.1181747f };

static __device__ inline uint_t  fbits(float f){ return __builtin_bit_cast(uint_t, f); }
static __device__ inline ushort_t f2b(float f){
    uint_t u = fbits(f);
    return (ushort_t)((u + 0x7fffu + ((u >> 16) & 1u)) >> 16);
}
static __device__ inline float b2f(ushort_t h){ return __builtin_bit_cast(float, (uint_t)h << 16); }
static __device__ inline ulong_t pack4(float4 v){      // RNE
    return (ulong_t)f2b(v.x) | ((ulong_t)f2b(v.y) << 16) |
           ((ulong_t)f2b(v.z) << 32) | ((ulong_t)f2b(v.w) << 48);
}
static __device__ inline ulong_t pack4t(float4 v){     // truncation (cheap)
    uint_t d0 = (fbits(v.x) >> 16) | (fbits(v.y) & 0xffff0000u);
    uint_t d1 = (fbits(v.z) >> 16) | (fbits(v.w) & 0xffff0000u);
    return (ulong_t)d0 | ((ulong_t)d1 << 32);
}
static __device__ inline float fast_tanh(float x){
    const float e = __expf(2.0f * x);
    return 1.0f - 2.0f / (e + 1.0f);
}
static __device__ inline void gload_lds16(const void* g, void* l){
    __builtin_amdgcn_global_load_lds(
        (const __attribute__((address_space(1))) unsigned int*)g,
        (__attribute__((address_space(3))) unsigned int*)l, 16, 0, 0);
}

// ---------------------------------------------------------------------------
// pack_wq: FOLDED KAN weights (spline + silu-as-spline), frag order, KS=8.
// wq[ks][ss(8)][t(4)][ct(4)][ln(64)][j(8)]; i = ks*128 + ss*16 + t*4 + (ln>>4)
// value = spline_w[o][i][j]*scaler[o][i] + base_w[o][i]*KC[j]
// ---------------------------------------------------------------------------
__global__ __launch_bounds__(256) void pack_wq(
    const float* __restrict__ base_w,
    const float* __restrict__ spline_w,
    const float* __restrict__ scaler,
    ushort_t* __restrict__ wq)
{
    const int e = blockIdx.x * 256 + threadIdx.x;   // 524288
    const int j  = e & 7;
    const int ln = (e >> 3) & 63;
    const int ct = (e >> 9) & 3;
    const int t  = (e >> 11) & 3;
    const int ss = (e >> 13) & 7;
    const int ks = e >> 16;
    const int o = ct * 16 + (ln & 15);
    const int g = ln >> 4;
    const int i = ks * 128 + ss * 16 + t * 4 + g;
    const float v = spline_w[(o * KIN_ + i) * 8 + j] * scaler[o * KIN_ + i]
                  + base_w[o * KIN_ + i] * KC[j];
    wq[e] = f2b(v);
}

// ---------------------------------------------------------------------------
// pack_wb2: wb[1024][768] bf16 (rows 0..511 Wx, 512..1023 Wy)
// ---------------------------------------------------------------------------
__global__ __launch_bounds__(256) void pack_wb2(
    const float* __restrict__ Wx,
    const float* __restrict__ Wy,
    ushort_t* __restrict__ wb)
{
    const int e = blockIdx.x * 256 + threadIdx.x;   // 786432
    const float v = (e < 512 * TF_) ? Wx[e] : Wy[e - 512 * TF_];
    wb[e] = f2b(v);
}

// ---------------------------------------------------------------------------
// pack_wfq: Wf frag order, bf16 (r8-proven tail).
// ---------------------------------------------------------------------------
__global__ __launch_bounds__(256) void pack_wfq(
    const float* __restrict__ Wf, ushort_t* __restrict__ wfq)
{
    const int e = blockIdx.x * 256 + threadIdx.x;   // 49152
    const int jj  = e & 7;
    const int ln  = (e >> 3) & 63;
    const int rt  = (e >> 9) & 3;
    const int s   = (e >> 11) & 1;
    const int wvt = (e >> 12) & 1;
    const int tb  = e >> 13;         // 0..5
    const int tf = tb * 128 + wvt * 64 + rt * 16 + (ln & 15);
    const int o  = s * 32 + (ln >> 4) * 8 + jj;
    wfq[e] = f2b(Wf[(size_t)tf * 64 + o]);
}

// ---------------------------------------------------------------------------
// xcvt: xbf[m][k] bf16  <-  Xs[b][t][n][f] fp32  (unchanged)
// ---------------------------------------------------------------------------
__global__ __launch_bounds__(256) void xcvt_kernel(
    const float* __restrict__ Xs, ushort_t* __restrict__ xbf)
{
    __shared__ __align__(16) char lds[32 * 1552];
    const int tid = threadIdx.x;
    const int n0  = blockIdx.x * 32;
    const int bb  = blockIdx.y;
    const int nl  = (tid & 63) >> 1;
    const int f4  = (tid & 1) * 4;
    const int tq  = tid >> 6;
    #pragma unroll 4
    for (int u = 0; u < 24; u++) {
        const int t = u * 4 + tq;
        const float4 v = *(const float4*)(Xs + (size_t)bb * (T_ * N_ * F_)
                                             + (size_t)t * (N_ * F_)
                                             + (size_t)(n0 + nl) * F_ + f4);
        *(ulong_t*)(lds + nl * 1552 + t * 16 + f4 * 2) = pack4t(v);
    }
    __syncthreads();
    #pragma unroll 4
    for (int u = 0; u < 12; u++) {
        const int c   = u * 256 + tid;      // 0..3071
        const int row = c / 96;
        const int col = c - row * 96;
        const uintx4 val = *(const uintx4*)(lds + row * 1552 + col * 16);
        *(uintx4*)(xbf + (size_t)(bb * 512 + n0 + row) * TF_ + col * 8) = val;
    }
}

// ---------------------------------------------------------------------------
// gemm_tanh_v7 (unchanged, proven).
// ---------------------------------------------------------------------------
__global__ __launch_bounds__(512, 2) void gemm_tanh_v7(
    const ushort_t* __restrict__ xbf,
    const ushort_t* __restrict__ wb,
    const float* __restrict__ bias,
    ushort_t* __restrict__ ht, int z)
{
    __shared__ __align__(16) char smem[32768];

    const int tid = threadIdx.x;
    const int wv  = tid >> 6;          // 0..7
    const int ln  = tid & 63;
    const int lr  = ln & 15;
    const int hi  = ln >> 4;
    const int wm  = wv >> 2;           // m-half
    const int wj  = wv & 3;            // j-quarter (32 cols)

    const int m0  = blockIdx.x * 128;
    const int jl0 = blockIdx.y * 128;
    const int j0  = z * 512 + jl0;

    const int r_l = ln >> 3;                    // row within 8-row region
    const int ck  = ((ln & 7) ^ r_l) * 8;       // inverse-swizzled src chunk

    f32x4 acc[4][2] = {};

    for (int kt = 0; kt < 12; kt++) {
        __syncthreads();
        #pragma unroll
        for (int s = 0; s < 2; s++) {
            const int reg = s * 8 + wv;          // 0..15
            const int row = reg * 8 + r_l;
            gload_lds16(xbf + (size_t)(m0 + row) * TF_ + kt * 64 + ck,
                        smem + reg * 1024 + ln * 16);
            gload_lds16(wb + (size_t)(j0 + row) * TF_ + kt * 64 + ck,
                        smem + 16384 + reg * 1024 + ln * 16);
        }
        __syncthreads();

        #pragma unroll
        for (int h = 0; h < 2; h++) {
            const int g = h * 4 + hi;
            short8 a[4], b[2];
            #pragma unroll
            for (int rt = 0; rt < 4; rt++) {
                const int r = wm * 64 + rt * 16 + lr;
                a[rt] = *(short8*)(smem + r * 128 + ((g ^ (r & 7)) * 16));
            }
            #pragma unroll
            for (int ct = 0; ct < 2; ct++) {
                const int r = wj * 32 + ct * 16 + lr;
                b[ct] = *(short8*)(smem + 16384 + r * 128 + ((g ^ (r & 7)) * 16));
            }
            #pragma unroll
            for (int rt = 0; rt < 4; rt++)
                #pragma unroll
                for (int ct = 0; ct < 2; ct++)
                    acc[rt][ct] = __builtin_amdgcn_mfma_f32_16x16x32_bf16(
                        a[rt], b[ct], acc[rt][ct], 0, 0, 0);
        }
    }

    // epilogue: tanh -> bf16 LDS [j 128][m 128] (16B-slot ^ (j&15)) -> ht
    __syncthreads();
    #pragma unroll
    for (int ct = 0; ct < 2; ct++) {
        const int j = wj * 32 + ct * 16 + lr;
        const float bvv = bias[jl0 + j];
        #pragma unroll
        for (int rt = 0; rt < 4; rt++) {
            const f32x4 v = acc[rt][ct];
            float4 tv;
            tv.x = fast_tanh(v[0] + bvv);
            tv.y = fast_tanh(v[1] + bvv);
            tv.z = fast_tanh(v[2] + bvv);
            tv.w = fast_tanh(v[3] + bvv);
            const int slot = wm * 8 + rt * 2 + (hi >> 1);
            *(ulong_t*)(smem + j * 256 + ((slot ^ (j & 15)) * 16) + (hi & 1) * 8)
                = pack4(tv);
        }
    }
    __syncthreads();
    {
        const int j  = tid >> 2;             // 0..127
        const int q4 = tid & 3;
        ushort_t* dst = ht + (size_t)(j0 + j) * M_ + m0 + q4 * 32;
        #pragma unroll
        for (int w = 0; w < 4; w++) {
            const int slot = q4 * 4 + w;
            short8 val = *(short8*)(smem + j * 256 + ((slot ^ (j & 15)) * 16));
            *(short8*)(dst + w * 8) = val;
        }
    }
}

// ---------------------------------------------------------------------------
// kan_v10b: silu folded into spline weights -> 32 uniform iterations.
// hts tile in LDS (swizzled, conflict-free); 2 iters per phase (16 phases,
// 1 barrier each, 8KB ping-pong weight buffers, register-staged 2 ahead).
// FIX vs r13: wB refill loads phase p+3 (was p+2 -> stale-weight bug).
// 128 rows/block (4 waves x 32 rows, acc[2][4]); grid (128, 8); LDS 48KB.
// ---------------------------------------------------------------------------
static __device__ inline short8 shift_pack(float b0, float b1, float b2, float b3, int si)
{
    const uint_t d0 = (fbits(b0) >> 16) | (fbits(b1) & 0xffff0000u);
    const uint_t d1 = (fbits(b2) >> 16) | (fbits(b3) & 0xffff0000u);
    const ulong_t P = (ulong_t)d0 | ((ulong_t)d1 << 32);
    const int sh = si << 4;
    const ulong_t Plo = P << (sh & 63);
    const ulong_t Phi = P >> ((64 - sh) & 63);
    ulongx2 pr;
    pr.x = (si == 4) ? 0ull : Plo;
    pr.y = (si == 0) ? 0ull : ((si == 4) ? P : Phi);
    return __builtin_bit_cast(short8, pr);
}

static __device__ inline void eval_bases2(float x0, float x1, short8& a0, short8& a1)
{
    f32x2 x = {x0, x1};
    f32x2 v = x * 2.5f + 2.5f;
    f32x2 sf = __builtin_elementwise_floor(v);
    sf = __builtin_elementwise_min(sf, (f32x2){4.0f, 4.0f});
    const f32x2 u  = v - sf;
    const f32x2 u2 = u * u;
    const f32x2 u3 = u2 * u;
    const f32x2 omu = 1.0f - u;
    const f32x2 omu3 = omu * omu * omu;
    const f32x2 B0 = omu3 * (1.0f / 6.0f);
    const f32x2 B3 = u3 * (1.0f / 6.0f);
    const f32x2 B1 = (u3 * 0.5f + (2.0f / 3.0f)) - u2;
    const f32x2 B2 = 1.0f - B0 - B1 - B3;
    a0 = shift_pack(B0[0], B1[0], B2[0], B3[0], (int)sf[0]);
    a1 = shift_pack(B0[1], B1[1], B2[1], B3[1], (int)sf[1]);
}

__global__ __launch_bounds__(256) void kan_v10b(
    const ushort_t* __restrict__ ht,
    const ushort_t* __restrict__ wq,
    _Float16* __restrict__ kanp)
{
    __shared__ __align__(16) char lds[49152];   // hts 32K (swizzled) + 2x8K wbuf

    const int tid = threadIdx.x;
    const int wv  = tid >> 6;
    const int ln  = tid & 63;
    const int g   = ln >> 4;
    const int lr  = ln & 15;
    const int m0  = blockIdx.x * 128;
    const int ks  = blockIdx.y;
    const int iB  = ks * 128;

    const ushort_t* wqk = wq + (size_t)ks * 65536;

    // ---- prologue: stage hts (inverse-swizzled source) + phase0 frags ----
    #pragma unroll
    for (int c = 0; c < 8; c++) {
        const int ll = wv * 8 + c;                   // 0..31
        const int il = ll * 4 + (ln >> 4);           // 0..127
        const int chunk = ln & 15;
        const int rowst = (chunk ^ ((il & 3) << 1)) * 8;   // inverse swizzle
        gload_lds16(ht + (size_t)(iB + il) * M_ + m0 + rowst,
                    lds + ll * 1024 + (ln & 15) * 16 + (ln >> 4) * 256);
    }
    gload_lds16(wqk + (size_t)wv * 512 + ln * 8,
                lds + 32768 + wv * 1024 + ln * 16);
    gload_lds16(wqk + (size_t)(4 + wv) * 512 + ln * 8,
                lds + 32768 + (4 + wv) * 1024 + ln * 16);
    // register pipeline: phase1 (wA*), phase2 (wB*)
    short8 wA0 = *(const short8*)(wqk + (size_t)(8 + wv) * 512 + ln * 8);
    short8 wA1 = *(const short8*)(wqk + (size_t)(12 + wv) * 512 + ln * 8);
    short8 wB0 = *(const short8*)(wqk + (size_t)(16 + wv) * 512 + ln * 8);
    short8 wB1 = *(const short8*)(wqk + (size_t)(20 + wv) * 512 + ln * 8);
    __syncthreads();

    // per-lane swizzled read bases (row0 = wv*32+lr, row1 = +16)
    const int hb0 = g * 256 + ((wv * 64 + lr * 2) ^ (g << 5));
    const int hb1 = g * 256 + ((wv * 64 + 32 + lr * 2) ^ (g << 5));

    f32x4 acc[2][4] = {};

    #pragma unroll 4
    for (int p = 0; p < 16; ++p) {
        char* rb = lds + 32768 + (p & 1) * 8192;
        short8 bfr[8];
        #pragma unroll
        for (int f = 0; f < 8; f++)
            bfr[f] = *(short8*)(rb + f * 1024 + ln * 16);

        // write phase p+1 frags (loaded 2 phases back), refill pipeline
        if (p < 15) {
            char* wbuf = lds + 32768 + ((p + 1) & 1) * 8192;
            *(short8*)(wbuf + wv * 1024 + ln * 16)       = wA0;
            *(short8*)(wbuf + (4 + wv) * 1024 + ln * 16) = wA1;
        }
        wA0 = wB0; wA1 = wB1;
        if (p < 13) {   // FIX: wB must hold phase p+3 (frags (p+3)*8 ..)
            wB0 = *(const short8*)(wqk + (size_t)((p + 3) * 8 + wv) * 512 + ln * 8);
            wB1 = *(const short8*)(wqk + (size_t)((p + 3) * 8 + 4 + wv) * 512 + ln * 8);
        }

        const int itA = 2 * p, itB = 2 * p + 1;
        short8 a0, a1, a2, a3;
        eval_bases2(b2f(*(const ushort_t*)(lds + hb0 + itA * 1024)),
                    b2f(*(const ushort_t*)(lds + hb1 + itA * 1024)), a0, a1);
        eval_bases2(b2f(*(const ushort_t*)(lds + hb0 + itB * 1024)),
                    b2f(*(const ushort_t*)(lds + hb1 + itB * 1024)), a2, a3);

        acc[0][0] = __builtin_amdgcn_mfma_f32_16x16x32_bf16(a0, bfr[0], acc[0][0], 0, 0, 0);
        acc[0][1] = __builtin_amdgcn_mfma_f32_16x16x32_bf16(a0, bfr[1], acc[0][1], 0, 0, 0);
        acc[0][2] = __builtin_amdgcn_mfma_f32_16x16x32_bf16(a0, bfr[2], acc[0][2], 0, 0, 0);
        acc[0][3] = __builtin_amdgcn_mfma_f32_16x16x32_bf16(a0, bfr[3], acc[0][3], 0, 0, 0);
        acc[1][0] = __builtin_amdgcn_mfma_f32_16x16x32_bf16(a1, bfr[0], acc[1][0], 0, 0, 0);
        acc[1][1] = __builtin_amdgcn_mfma_f32_16x16x32_bf16(a1, bfr[1], acc[1][1], 0, 0, 0);
        acc[1][2] = __builtin_amdgcn_mfma_f32_16x16x32_bf16(a1, bfr[2], acc[1][2], 0, 0, 0);
        acc[1][3] = __builtin_amdgcn_mfma_f32_16x16x32_bf16(a1, bfr[3], acc[1][3], 0, 0, 0);
        acc[0][0] = __builtin_amdgcn_mfma_f32_16x16x32_bf16(a2, bfr[4], acc[0][0], 0, 0, 0);
        acc[0][1] = __builtin_amdgcn_mfma_f32_16x16x32_bf16(a2, bfr[5], acc[0][1], 0, 0, 0);
        acc[0][2] = __builtin_amdgcn_mfma_f32_16x16x32_bf16(a2, bfr[6], acc[0][2], 0, 0, 0);
        acc[0][3] = __builtin_amdgcn_mfma_f32_16x16x32_bf16(a2, bfr[7], acc[0][3], 0, 0, 0);
        acc[1][0] = __builtin_amdgcn_mfma_f32_16x16x32_bf16(a3, bfr[4], acc[1][0], 0, 0, 0);
        acc[1][1] = __builtin_amdgcn_mfma_f32_16x16x32_bf16(a3, bfr[5], acc[1][1], 0, 0, 0);
        acc[1][2] = __builtin_amdgcn_mfma_f32_16x16x32_bf16(a3, bfr[6], acc[1][2], 0, 0, 0);
        acc[1][3] = __builtin_amdgcn_mfma_f32_16x16x32_bf16(a3, bfr[7], acc[1][3], 0, 0, 0);

        __syncthreads();   // rb reads done + p+1 writes visible
    }

    // C layout: col (o) = ct*16+lr, row = rt*16 + g*4 + q
    #pragma unroll
    for (int rt = 0; rt < 2; rt++) {
        #pragma unroll
        for (int ct = 0; ct < 4; ct++) {
            const int o = ct * 16 + lr;
            #pragma unroll
            for (int q = 0; q < 4; q++) {
                const size_t row = (size_t)(m0 + wv * 32 + rt * 16 + g * 4 + q);
                kanp[(size_t)ks * (M_ * 64) + row * 64 + o] = (_Float16)acc[rt][ct][q];
            }
        }
    }
}

// ---------------------------------------------------------------------------
// reduce_kan: kanr[m][o] bf16 = sum_ks kanp_fp16[ks][m][o]  (r8-proven)
// ---------------------------------------------------------------------------
__global__ __launch_bounds__(256) void reduce_kan(
    const _Float16* __restrict__ kanp, ushort_t* __restrict__ kanr)
{
    const int e8 = blockIdx.x * 256 + threadIdx.x;   // 131072 threads
    const size_t base = (size_t)e8 * 8;
    float s[8] = {};
    #pragma unroll
    for (int p = 0; p < KS_; p++) {
        const halfx8 v = *(const halfx8*)(kanp + (size_t)p * (M_ * 64) + base);
        #pragma unroll
        for (int j = 0; j < 8; j++) s[j] += (float)v[j];
    }
    float4 s0 = make_float4(s[0], s[1], s[2], s[3]);
    float4 s1 = make_float4(s[4], s[5], s[6], s[7]);
    ulongx2 outv;
    outv.x = pack4(s0);
    outv.y = pack4(s1);
    *(ulongx2*)(kanr + base) = outv;
}

// ---------------------------------------------------------------------------
// final_v2 (r8-proven): out = kanr @ Wf^T + bf, MFMA, float4 stores.
// ---------------------------------------------------------------------------
__global__ __launch_bounds__(256) void final_v2(
    const ushort_t* __restrict__ kanr,
    const ushort_t* __restrict__ wfq,
    const float* __restrict__ bf,
    float* __restrict__ out)
{
    const int tid = threadIdx.x;
    const int wv  = tid >> 6;
    const int ln  = tid & 63;
    const int lr  = ln & 15;
    const int hi  = ln >> 4;
    const int wvm = wv >> 1;
    const int wvt = wv & 1;
    const int mb  = blockIdx.x;
    const int tb  = blockIdx.y;

    f32x4 acc[4][4] = {};

    #pragma unroll
    for (int s = 0; s < 2; s++) {
        short8 afr[4], bfr[4];
        #pragma unroll
        for (int rt = 0; rt < 4; rt++) {
            const size_t idx = ((size_t)(((tb * 2 + wvt) * 2 + s) * 4 + rt)) * 64 + ln;
            afr[rt] = ((const short8*)wfq)[idx];
        }
        #pragma unroll
        for (int ct = 0; ct < 4; ct++) {
            const int m = mb * 128 + wvm * 64 + ct * 16 + lr;
            bfr[ct] = *(const short8*)(kanr + (size_t)m * 64 + s * 32 + hi * 8);
        }
        #pragma unroll
        for (int rt = 0; rt < 4; rt++)
            #pragma unroll
            for (int ct = 0; ct < 4; ct++)
                acc[rt][ct] = __builtin_amdgcn_mfma_f32_16x16x32_bf16(
                    afr[rt], bfr[ct], acc[rt][ct], 0, 0, 0);
    }

    #pragma unroll
    for (int rt = 0; rt < 4; rt++) {
        const int tf0 = tb * 128 + wvt * 64 + rt * 16 + hi * 4;
        const float4 b4 = *(const float4*)&bf[tf0];
        const int t  = tf0 >> 3;
        const int f0 = tf0 & 7;
        #pragma unroll
        for (int ct = 0; ct < 4; ct++) {
            const int m = mb * 128 + wvm * 64 + ct * 16 + lr;
            const int bb = m >> 9;
            const int n  = m & 511;
            const f32x4 v = acc[rt][ct];
            float4 o4 = make_float4(v[0] + b4.x, v[1] + b4.y, v[2] + b4.z, v[3] + b4.w);
            *(float4*)&out[(size_t)bb * (T_ * N_ * F_)
                           + (size_t)t * (N_ * F_)
                           + (size_t)n * F_ + f0] = o4;
        }
    }
}

// ---------------------------------------------------------------------------
extern "C" void kernel_launch(void* const* d_in, const int* in_sizes, int n_in,
                              void* d_out, int out_size, void* d_ws, size_t ws_size,
                              hipStream_t stream)
{
    const float* X      = (const float*)d_in[0];
    const float* Y      = (const float*)d_in[1];
    const float* Wx     = (const float*)d_in[2];
    const float* bx     = (const float*)d_in[3];
    const float* Wy     = (const float*)d_in[4];
    const float* by     = (const float*)d_in[5];
    const float* base_w = (const float*)d_in[6];
    const float* spline_w = (const float*)d_in[7];
    const float* spline_scaler = (const float*)d_in[8];
    const float* Wf     = (const float*)d_in[9];
    const float* bf     = (const float*)d_in[10];

    float* out = (float*)d_out;
    ushort_t* ht   = (ushort_t*)((char*)d_ws + HT_B);
    ushort_t* wq   = (ushort_t*)((char*)d_ws + WQ_B);
    ushort_t* wb   = (ushort_t*)((char*)d_ws + WB_B);
    ushort_t* xbf  = (ushort_t*)((char*)d_ws + SH_B);   // overlaps kanp
    _Float16* kanp = (_Float16*)((char*)d_ws + SH_B);
    ushort_t* kanr = (ushort_t*)((char*)d_ws + KANR_B);
    ushort_t* wfq  = (ushort_t*)((char*)d_ws + WFQ_B);

    pack_wq<<<2048, 256, 0, stream>>>(base_w, spline_w, spline_scaler, wq);
    pack_wb2<<<3072, 256, 0, stream>>>(Wx, Wy, wb);
    pack_wfq<<<192, 256, 0, stream>>>(Wf, wfq);

    // X half: convert then GEMM (xbf reused for Y afterwards)
    xcvt_kernel<<<dim3(16, 32), 256, 0, stream>>>(X, xbf);
    gemm_tanh_v7<<<dim3(128, 4), 512, 0, stream>>>(xbf, wb, bx, ht, 0);
    xcvt_kernel<<<dim3(16, 32), 256, 0, stream>>>(Y, xbf);
    gemm_tanh_v7<<<dim3(128, 4), 512, 0, stream>>>(xbf, wb, by, ht, 1);

    kan_v10b<<<dim3(M_ / 128, KS_), 256, 0, stream>>>(ht, wq, kanp);
    reduce_kan<<<512, 256, 0, stream>>>(kanp, kanr);
    final_v2<<<dim3(128, 6), 256, 0, stream>>>(kanr, wfq, bf, out);
}